// Round 5
// baseline (3967.009 us; speedup 1.0000x reference)
//
#include <hip/hip_runtime.h>
#include <math.h>

#define B_   256
#define C_   2048
#define D_   192
#define EPSf 1e-5f
#define BLAS_Q 384   // OpenBLAS SGEMM_DEFAULT_Q (Haswell/Zen) — K-block size

// ---------------------------------------------------------------------------
// numpy pairwise-sum emulation, n=96 blocks (numpy: n=192 -> pw96(a)+pw96(a+96);
// each 96-block: 8 accumulators, r[j] += a[8i+j], combined
// ((r0+r1)+(r2+r3))+((r4+r5)+(r6+r7)), no tail). Squares rounded separately
// (np computes X*X then sums) -> __fmul_rn to forbid FMA contraction.
// ---------------------------------------------------------------------------
__device__ __forceinline__ float pw96_sq_f4(const float4* a4) {
    float r0 = 0.f, r1 = 0.f, r2 = 0.f, r3 = 0.f, r4 = 0.f, r5 = 0.f, r6 = 0.f, r7 = 0.f;
#pragma unroll
    for (int i = 0; i < 12; ++i) {
        const float4 v0 = a4[2 * i], v1 = a4[2 * i + 1];
        r0 += __fmul_rn(v0.x, v0.x); r1 += __fmul_rn(v0.y, v0.y);
        r2 += __fmul_rn(v0.z, v0.z); r3 += __fmul_rn(v0.w, v0.w);
        r4 += __fmul_rn(v1.x, v1.x); r5 += __fmul_rn(v1.y, v1.y);
        r6 += __fmul_rn(v1.z, v1.z); r7 += __fmul_rn(v1.w, v1.w);
    }
    return ((r0 + r1) + (r2 + r3)) + ((r4 + r5) + (r6 + r7));
}

__device__ __forceinline__ float pw96_sq_s(const float* a) {
    float r0 = 0.f, r1 = 0.f, r2 = 0.f, r3 = 0.f, r4 = 0.f, r5 = 0.f, r6 = 0.f, r7 = 0.f;
#pragma unroll
    for (int i = 0; i < 12; ++i) {
        r0 += __fmul_rn(a[8 * i + 0], a[8 * i + 0]);
        r1 += __fmul_rn(a[8 * i + 1], a[8 * i + 1]);
        r2 += __fmul_rn(a[8 * i + 2], a[8 * i + 2]);
        r3 += __fmul_rn(a[8 * i + 3], a[8 * i + 3]);
        r4 += __fmul_rn(a[8 * i + 4], a[8 * i + 4]);
        r5 += __fmul_rn(a[8 * i + 5], a[8 * i + 5]);
        r6 += __fmul_rn(a[8 * i + 6], a[8 * i + 6]);
        r7 += __fmul_rn(a[8 * i + 7], a[8 * i + 7]);
    }
    return ((r0 + r1) + (r2 + r3)) + ((r4 + r5) + (r6 + r7));
}

// ---------------------------------------------------------------------------
// Kernel 1: pooled[b,c] = mean over 192
// ---------------------------------------------------------------------------
__global__ __launch_bounds__(256) void pool_kernel(const float* __restrict__ x,
                                                   float* __restrict__ pooled) {
    const int row  = blockIdx.x * 4 + (threadIdx.x >> 6);
    const int lane = threadIdx.x & 63;
    const float* r = x + (size_t)row * D_;
    float s = 0.f;
    if (lane < 48) {
        const float4 v = ((const float4*)r)[lane];
        s = v.x + v.y + v.z + v.w;
    }
#pragma unroll
    for (int off = 32; off > 0; off >>= 1) s += __shfl_down(s, off);
    if (lane == 0) pooled[row] = s * (1.f / 192.f);
}

// ---------------------------------------------------------------------------
// Kernel 2: per-sample kmeans, bit-exact emulation of numpy/OpenBLAS fp32:
//  - xs, cs: numpy pairwise sums (96+96, 8-acc blocks)
//  - dots (X@cent.T, K=192 <= Q): single sequential fmaf chain over d
//  - d2 = (xs - 2*dot) + cs, per-op fp32 rounding
//  - center sums (oh.T@X, K=2048): K-blocked by Q=384; within-block
//    sequential adds in ascending c (fma(0,x,acc)=acc exact), one add per
//    block combine — emulates sgemm beta-accumulate across k-blocks
//  - division by exact float count; keep old center when count==0
// Early-exit on unchanged assignments (deterministic fixed point).
// ---------------------------------------------------------------------------
__global__ __launch_bounds__(256) void kmeans_kernel(const float* __restrict__ x,
                                                     unsigned char* __restrict__ ids_out) {
    const int b = blockIdx.x, t = threadIdx.x;
    const int lane = t & 63;
    const float* X = x + (size_t)b * (C_ * (size_t)D_);

    __shared__ __align__(16) float cent[4][192];
    __shared__ float xs_s[C_];
    __shared__ float cs4[4];
    __shared__ int   cnt[4];
    __shared__ int   changed;
    __shared__ unsigned char ids[C_];

    if (t < 192) {
        cent[0][t] = X[(size_t)0    * D_ + t];
        cent[1][t] = X[(size_t)512  * D_ + t];
        cent[2][t] = X[(size_t)1024 * D_ + t];
        cent[3][t] = X[(size_t)1536 * D_ + t];
    }
    for (int j = 0; j < 8; ++j) {
        const int c = t + 256 * j;
        const float4* r4 = (const float4*)(X + (size_t)c * D_);
        xs_s[c] = pw96_sq_f4(r4) + pw96_sq_f4(r4 + 24);
        ids[c]  = 255;
    }
    __syncthreads();

    for (int iter = 0;; ++iter) {
        if (t < 4) {
            cs4[t] = pw96_sq_s(cent[t]) + pw96_sq_s(cent[t] + 96);
            cnt[t] = 0;
        }
        if (t == 0) changed = 0;
        __syncthreads();

        const float q0 = cs4[0], q1 = cs4[1], q2 = cs4[2], q3 = cs4[3];

        // ---- Phase A: assignment, sequential fmaf chains per (c,k) ----
        int lc0 = 0, lc1 = 0, lc2 = 0, lc3 = 0, mych = 0;
        for (int j = 0; j < 8; ++j) {
            const int c = t + 256 * j;
            const float4* r4 = (const float4*)(X + (size_t)c * D_);
            float d0 = 0.f, d1 = 0.f, d2 = 0.f, d3 = 0.f;
#pragma unroll 8
            for (int i = 0; i < 48; ++i) {
                const float4 a  = r4[i];
                const float4 c0 = *(const float4*)&cent[0][4 * i];
                const float4 c1 = *(const float4*)&cent[1][4 * i];
                const float4 c2 = *(const float4*)&cent[2][4 * i];
                const float4 c3 = *(const float4*)&cent[3][4 * i];
                d0 = fmaf(a.x, c0.x, d0); d0 = fmaf(a.y, c0.y, d0);
                d0 = fmaf(a.z, c0.z, d0); d0 = fmaf(a.w, c0.w, d0);
                d1 = fmaf(a.x, c1.x, d1); d1 = fmaf(a.y, c1.y, d1);
                d1 = fmaf(a.z, c1.z, d1); d1 = fmaf(a.w, c1.w, d1);
                d2 = fmaf(a.x, c2.x, d2); d2 = fmaf(a.y, c2.y, d2);
                d2 = fmaf(a.z, c2.z, d2); d2 = fmaf(a.w, c2.w, d2);
                d3 = fmaf(a.x, c3.x, d3); d3 = fmaf(a.y, c3.y, d3);
                d3 = fmaf(a.z, c3.z, d3); d3 = fmaf(a.w, c3.w, d3);
            }
            const float xv = xs_s[c];
            const float e0 = (xv - 2.0f * d0) + q0;
            const float e1 = (xv - 2.0f * d1) + q1;
            const float e2 = (xv - 2.0f * d2) + q2;
            const float e3 = (xv - 2.0f * d3) + q3;
            int id = 0; float best = e0;
            if (e1 < best) { best = e1; id = 1; }
            if (e2 < best) { best = e2; id = 2; }
            if (e3 < best) { best = e3; id = 3; }
            lc0 += (id == 0); lc1 += (id == 1); lc2 += (id == 2); lc3 += (id == 3);
            mych |= (ids[c] != (unsigned char)id);
            ids[c] = (unsigned char)id;
        }
#pragma unroll
        for (int off = 32; off > 0; off >>= 1) {
            lc0 += __shfl_down(lc0, off);
            lc1 += __shfl_down(lc1, off);
            lc2 += __shfl_down(lc2, off);
            lc3 += __shfl_down(lc3, off);
        }
        if (lane == 0) {
            atomicAdd(&cnt[0], lc0); atomicAdd(&cnt[1], lc1);
            atomicAdd(&cnt[2], lc2); atomicAdd(&cnt[3], lc3);
        }
        if (mych) changed = 1;
        __syncthreads();

        if (changed == 0 || iter == 10) break;   // converged -> exact fixed point

        // ---- Phase B: centers. Thread t owns dim d=t; ascending c within
        // Q=384 K-blocks (sequential adds), blocks combined sequentially. ----
        if (t < 192) {
            float t0 = 0.f, t1 = 0.f, t2 = 0.f, t3 = 0.f;
            for (int kb = 0; kb < C_; kb += BLAS_Q) {
                const int ke = (kb + BLAS_Q < C_) ? (kb + BLAS_Q) : C_;
                float s0 = 0.f, s1 = 0.f, s2 = 0.f, s3 = 0.f;
                for (int c = kb; c < ke; ++c) {
                    const float xv = X[(size_t)c * D_ + t];
                    const int id = ids[c];
                    s0 += (id == 0) ? xv : 0.0f;
                    s1 += (id == 1) ? xv : 0.0f;
                    s2 += (id == 2) ? xv : 0.0f;
                    s3 += (id == 3) ? xv : 0.0f;
                }
                t0 += s0; t1 += s1; t2 += s2; t3 += s3;
            }
            if (cnt[0] > 0) cent[0][t] = t0 / (float)cnt[0];
            if (cnt[1] > 0) cent[1][t] = t1 / (float)cnt[1];
            if (cnt[2] > 0) cent[2][t] = t2 / (float)cnt[2];
            if (cnt[3] > 0) cent[3][t] = t3 / (float)cnt[3];
        }
        __syncthreads();
    }

    for (int c = t; c < C_; c += 256) ids_out[(size_t)b * C_ + c] = ids[c];
}

// ---------------------------------------------------------------------------
__device__ __forceinline__ float bn_apply(float v, float g, float be, float m, float va) {
    return (v - m) / sqrtf(va + EPSf) * g + be;
}

// ---------------------------------------------------------------------------
// Kernel 3: batched 64x64-tiled GEMM, M=256, N=512, K=2048.
//  z==0: xg2 = bn2(relu(bn1(pooled@Wg^T + bg)))
//  z>=1: h1[k] = relu(bn(n1, maskedpooled@W1^T + b1)), mask = (ids==k)
// ---------------------------------------------------------------------------
__global__ __launch_bounds__(256) void gemm1_kernel(
    const float* __restrict__ pooled, const unsigned char* __restrict__ ids,
    const float* __restrict__ Wg, const float* __restrict__ bg,
    const float* __restrict__ g_gamma, const float* __restrict__ g_beta,
    const float* __restrict__ g_mean, const float* __restrict__ g_var,
    const float* __restrict__ gb_gamma, const float* __restrict__ gb_beta,
    const float* __restrict__ gb_mean, const float* __restrict__ gb_var,
    const float* __restrict__ W1, const float* __restrict__ b1,
    const float* __restrict__ n1_gamma, const float* __restrict__ n1_beta,
    const float* __restrict__ n1_mean, const float* __restrict__ n1_var,
    float* __restrict__ xg2, float* __restrict__ h1) {
    const int z = blockIdx.z;
    const int bn0 = blockIdx.x * 64, bm0 = blockIdx.y * 64;
    const float* Bmat = (z == 0) ? Wg : W1;
    __shared__ float As[32][68];
    __shared__ float Bs[32][68];
    float acc[4][4] = {};
    const int t = threadIdx.x;
    const int tx = t & 15, ty = t >> 4;

    for (int k0 = 0; k0 < 2048; k0 += 32) {
#pragma unroll
        for (int u = 0; u < 2; ++u) {
            const int idx = t + 256 * u;
            const int m = idx >> 3, kc = idx & 7;
            float4 v = *(const float4*)(pooled + (size_t)(bm0 + m) * 2048 + k0 + kc * 4);
            if (z > 0) {
                const unsigned int uu =
                    *(const unsigned int*)(ids + (size_t)(bm0 + m) * 2048 + k0 + kc * 4);
                const unsigned int k = (unsigned int)(z - 1);
                v.x = ((uu & 0xffu) == k) ? v.x : 0.f;
                v.y = (((uu >> 8) & 0xffu) == k) ? v.y : 0.f;
                v.z = (((uu >> 16) & 0xffu) == k) ? v.z : 0.f;
                v.w = (((uu >> 24) & 0xffu) == k) ? v.w : 0.f;
            }
            As[kc * 4 + 0][m] = v.x; As[kc * 4 + 1][m] = v.y;
            As[kc * 4 + 2][m] = v.z; As[kc * 4 + 3][m] = v.w;
            const float4 wv = *(const float4*)(Bmat + (size_t)(bn0 + m) * 2048 + k0 + kc * 4);
            Bs[kc * 4 + 0][m] = wv.x; Bs[kc * 4 + 1][m] = wv.y;
            Bs[kc * 4 + 2][m] = wv.z; Bs[kc * 4 + 3][m] = wv.w;
        }
        __syncthreads();
#pragma unroll 8
        for (int kk = 0; kk < 32; ++kk) {
            const float4 a = *(const float4*)&As[kk][ty * 4];
            const float4 wv = *(const float4*)&Bs[kk][tx * 4];
            const float av[4] = {a.x, a.y, a.z, a.w};
            const float bv[4] = {wv.x, wv.y, wv.z, wv.w};
#pragma unroll
            for (int i = 0; i < 4; ++i)
#pragma unroll
                for (int j = 0; j < 4; ++j) acc[i][j] += av[i] * bv[j];
        }
        __syncthreads();
    }

    const int m0 = bm0 + ty * 4, n0 = bn0 + tx * 4;
    if (z == 0) {
#pragma unroll
        for (int j = 0; j < 4; ++j) {
            const int n = n0 + j;
            const float bgv = bg[n];
            const float g1 = g_gamma[n], be1 = g_beta[n], mm1 = g_mean[n], vv1 = g_var[n];
            const float g2 = gb_gamma[n], be2 = gb_beta[n], mm2 = gb_mean[n], vv2 = gb_var[n];
#pragma unroll
            for (int i = 0; i < 4; ++i) {
                float v = acc[i][j] + bgv;
                v = bn_apply(v, g1, be1, mm1, vv1);
                v = fmaxf(v, 0.f);
                v = bn_apply(v, g2, be2, mm2, vv2);
                xg2[(size_t)(m0 + i) * 512 + n] = v;
            }
        }
    } else {
        const int k = z - 1;
#pragma unroll
        for (int j = 0; j < 4; ++j) {
            const int n = n0 + j;
            const float b1v = b1[n];
            const float g1 = n1_gamma[n], be1 = n1_beta[n], mm1 = n1_mean[n], vv1 = n1_var[n];
#pragma unroll
            for (int i = 0; i < 4; ++i) {
                float v = acc[i][j] + b1v;
                v = bn_apply(v, g1, be1, mm1, vv1);
                v = fmaxf(v, 0.f);
                h1[((size_t)k * 256 + (m0 + i)) * 512 + n] = v;
            }
        }
    }
}

// ---------------------------------------------------------------------------
// Kernel 4: h2 = relu(bn(n2, h1@W2^T + b2)); then per-branch bk BN;
// write y[b, k*128+p]. M=1024 (k*256+b), N=128, K=512.
// ---------------------------------------------------------------------------
__global__ __launch_bounds__(256) void gemm2_kernel(
    const float* __restrict__ h1, const float* __restrict__ W2,
    const float* __restrict__ b2,
    const float* __restrict__ n2_gamma, const float* __restrict__ n2_beta,
    const float* __restrict__ n2_mean, const float* __restrict__ n2_var,
    const float* __restrict__ bk_gamma, const float* __restrict__ bk_beta,
    const float* __restrict__ bk_mean, const float* __restrict__ bk_var,
    float* __restrict__ yv) {
    const int bn0 = blockIdx.x * 64, bm0 = blockIdx.y * 64;
    __shared__ float As[32][68];
    __shared__ float Bs[32][68];
    float acc[4][4] = {};
    const int t = threadIdx.x;
    const int tx = t & 15, ty = t >> 4;

    for (int k0 = 0; k0 < 512; k0 += 32) {
#pragma unroll
        for (int u = 0; u < 2; ++u) {
            const int idx = t + 256 * u;
            const int m = idx >> 3, kc = idx & 7;
            const float4 v = *(const float4*)(h1 + (size_t)(bm0 + m) * 512 + k0 + kc * 4);
            As[kc * 4 + 0][m] = v.x; As[kc * 4 + 1][m] = v.y;
            As[kc * 4 + 2][m] = v.z; As[kc * 4 + 3][m] = v.w;
            const float4 wv = *(const float4*)(W2 + (size_t)(bn0 + m) * 512 + k0 + kc * 4);
            Bs[kc * 4 + 0][m] = wv.x; Bs[kc * 4 + 1][m] = wv.y;
            Bs[kc * 4 + 2][m] = wv.z; Bs[kc * 4 + 3][m] = wv.w;
        }
        __syncthreads();
#pragma unroll 8
        for (int kk = 0; kk < 32; ++kk) {
            const float4 a = *(const float4*)&As[kk][ty * 4];
            const float4 wv = *(const float4*)&Bs[kk][tx * 4];
            const float av[4] = {a.x, a.y, a.z, a.w};
            const float bv[4] = {wv.x, wv.y, wv.z, wv.w};
#pragma unroll
            for (int i = 0; i < 4; ++i)
#pragma unroll
                for (int j = 0; j < 4; ++j) acc[i][j] += av[i] * bv[j];
        }
        __syncthreads();
    }

    const int m0 = bm0 + ty * 4, n0 = bn0 + tx * 4;
#pragma unroll
    for (int j = 0; j < 4; ++j) {
        const int n = n0 + j;
        const float b2v = b2[n];
        const float g1 = n2_gamma[n], be1 = n2_beta[n], mm1 = n2_mean[n], vv1 = n2_var[n];
#pragma unroll
        for (int i = 0; i < 4; ++i) {
            const int row = m0 + i;
            const int k = row >> 8, b = row & 255;
            float v = acc[i][j] + b2v;
            v = bn_apply(v, g1, be1, mm1, vv1);
            v = fmaxf(v, 0.f);
            const int pi = k * 128 + n;
            v = bn_apply(v, bk_gamma[pi], bk_beta[pi], bk_mean[pi], bk_var[pi]);
            yv[(size_t)b * 512 + pi] = v;
        }
    }
}

// ---------------------------------------------------------------------------
// Kernel 5: heads. x_pre = xg2@Wcg^T + bcg ; y_pre = y@Wck^T + bck
// ---------------------------------------------------------------------------
__global__ __launch_bounds__(128) void head_kernel(
    const float* __restrict__ xg2, const float* __restrict__ yv,
    const float* __restrict__ Wcg, const float* __restrict__ bcg,
    const float* __restrict__ Wck, const float* __restrict__ bck,
    float* __restrict__ out) {
    const int b = blockIdx.x, t = threadIdx.x;
    __shared__ float xr[512], yr[512];
    ((float4*)xr)[t] = ((const float4*)(xg2 + (size_t)b * 512))[t];
    ((float4*)yr)[t] = ((const float4*)(yv + (size_t)b * 512))[t];
    __syncthreads();
    if (t < 51) {
        float acc = 0.f;
        const float4* wr = (const float4*)(Wcg + (size_t)t * 512);
        const float4* xv = (const float4*)xr;
#pragma unroll 8
        for (int p = 0; p < 128; ++p) {
            const float4 w4 = wr[p], v4 = xv[p];
            acc += w4.x * v4.x + w4.y * v4.y + w4.z * v4.z + w4.w * v4.w;
        }
        out[(size_t)b * 51 + t] = acc + bcg[t];
    } else if (t >= 64 && t < 115) {
        const int n = t - 64;
        float acc = 0.f;
        const float4* wr = (const float4*)(Wck + (size_t)n * 512);
        const float4* yv4 = (const float4*)yr;
#pragma unroll 8
        for (int p = 0; p < 128; ++p) {
            const float4 w4 = wr[p], v4 = yv4[p];
            acc += w4.x * v4.x + w4.y * v4.y + w4.z * v4.z + w4.w * v4.w;
        }
        out[(size_t)(B_ * 51) + (size_t)b * 51 + n] = acc + bck[n];
    }
}

// ---------------------------------------------------------------------------
extern "C" void kernel_launch(void* const* d_in, const int* in_sizes, int n_in,
                              void* d_out, int out_size, void* d_ws, size_t ws_size,
                              hipStream_t stream) {
    const float* x        = (const float*)d_in[0];
    const float* Wg       = (const float*)d_in[1];
    const float* bg       = (const float*)d_in[2];
    const float* g_gamma  = (const float*)d_in[3];
    const float* g_beta   = (const float*)d_in[4];
    const float* g_mean   = (const float*)d_in[5];
    const float* g_var    = (const float*)d_in[6];
    const float* gb_gamma = (const float*)d_in[7];
    const float* gb_beta  = (const float*)d_in[8];
    const float* gb_mean  = (const float*)d_in[9];
    const float* gb_var   = (const float*)d_in[10];
    const float* Wcg      = (const float*)d_in[11];
    const float* bcg      = (const float*)d_in[12];
    const float* W1       = (const float*)d_in[13];
    const float* b1       = (const float*)d_in[14];
    const float* n1_gamma = (const float*)d_in[15];
    const float* n1_beta  = (const float*)d_in[16];
    const float* n1_mean  = (const float*)d_in[17];
    const float* n1_var   = (const float*)d_in[18];
    const float* W2       = (const float*)d_in[19];
    const float* b2       = (const float*)d_in[20];
    const float* n2_gamma = (const float*)d_in[21];
    const float* n2_beta  = (const float*)d_in[22];
    const float* n2_mean  = (const float*)d_in[23];
    const float* n2_var   = (const float*)d_in[24];
    const float* bk_gamma = (const float*)d_in[25];
    const float* bk_beta  = (const float*)d_in[26];
    const float* bk_mean  = (const float*)d_in[27];
    const float* bk_var   = (const float*)d_in[28];
    const float* Wck      = (const float*)d_in[29];
    const float* bck      = (const float*)d_in[30];
    float* out = (float*)d_out;

    float* pooled      = (float*)d_ws;                       // 524288 f
    unsigned char* ids = (unsigned char*)(pooled + 524288);  // 524288 B
    float* xg2         = (float*)(ids + 524288);             // 131072 f
    float* h1          = xg2 + 131072;                       // 524288 f
    float* yv          = h1 + 524288;                        // 131072 f

    pool_kernel<<<dim3((B_ * C_) / 4), dim3(256), 0, stream>>>(x, pooled);
    kmeans_kernel<<<dim3(B_), dim3(256), 0, stream>>>(x, ids);
    gemm1_kernel<<<dim3(8, 4, 5), dim3(256), 0, stream>>>(
        pooled, ids, Wg, bg, g_gamma, g_beta, g_mean, g_var,
        gb_gamma, gb_beta, gb_mean, gb_var, W1, b1,
        n1_gamma, n1_beta, n1_mean, n1_var, xg2, h1);
    gemm2_kernel<<<dim3(2, 16), dim3(256), 0, stream>>>(
        h1, W2, b2, n2_gamma, n2_beta, n2_mean, n2_var,
        bk_gamma, bk_beta, bk_mean, bk_var, yv);
    head_kernel<<<dim3(B_), dim3(128), 0, stream>>>(xg2, yv, Wcg, bcg, Wck, bck, out);
}

// Round 8
// 3767.815 us; speedup vs baseline: 1.0529x; 1.0529x over previous
//
#include <hip/hip_runtime.h>
#include <math.h>

#define B_   256
#define C_   2048
#define D_   192
#define EPSf 1e-5f
#define BLAS_Q 384   // OpenBLAS SGEMM_DEFAULT_Q — K-block size (validated in R5)

// ---------------------------------------------------------------------------
// numpy pairwise-sum emulation, n=96 blocks (numpy: n=192 -> pw96(a)+pw96(a+96);
// each 96-block: 8 accumulators, combined ((r0+r1)+(r2+r3))+((r4+r5)+(r6+r7))).
// Squares rounded separately -> __fmul_rn forbids FMA contraction.
// ---------------------------------------------------------------------------
__device__ __forceinline__ float pw96_sq_f4(const float4* a4) {
    float r0 = 0.f, r1 = 0.f, r2 = 0.f, r3 = 0.f, r4 = 0.f, r5 = 0.f, r6 = 0.f, r7 = 0.f;
#pragma unroll
    for (int i = 0; i < 12; ++i) {
        const float4 v0 = a4[2 * i], v1 = a4[2 * i + 1];
        r0 += __fmul_rn(v0.x, v0.x); r1 += __fmul_rn(v0.y, v0.y);
        r2 += __fmul_rn(v0.z, v0.z); r3 += __fmul_rn(v0.w, v0.w);
        r4 += __fmul_rn(v1.x, v1.x); r5 += __fmul_rn(v1.y, v1.y);
        r6 += __fmul_rn(v1.z, v1.z); r7 += __fmul_rn(v1.w, v1.w);
    }
    return ((r0 + r1) + (r2 + r3)) + ((r4 + r5) + (r6 + r7));
}

__device__ __forceinline__ float pw96_sq_s(const float* a) {
    float r0 = 0.f, r1 = 0.f, r2 = 0.f, r3 = 0.f, r4 = 0.f, r5 = 0.f, r6 = 0.f, r7 = 0.f;
#pragma unroll
    for (int i = 0; i < 12; ++i) {
        r0 += __fmul_rn(a[8 * i + 0], a[8 * i + 0]);
        r1 += __fmul_rn(a[8 * i + 1], a[8 * i + 1]);
        r2 += __fmul_rn(a[8 * i + 2], a[8 * i + 2]);
        r3 += __fmul_rn(a[8 * i + 3], a[8 * i + 3]);
        r4 += __fmul_rn(a[8 * i + 4], a[8 * i + 4]);
        r5 += __fmul_rn(a[8 * i + 5], a[8 * i + 5]);
        r6 += __fmul_rn(a[8 * i + 6], a[8 * i + 6]);
        r7 += __fmul_rn(a[8 * i + 7], a[8 * i + 7]);
    }
    return ((r0 + r1) + (r2 + r3)) + ((r4 + r5) + (r6 + r7));
}

// ---------------------------------------------------------------------------
// Kernel 1: pooled[b,c] = mean over 192 (exact R5 version — PASSED)
// ---------------------------------------------------------------------------
__global__ __launch_bounds__(256) void pool_kernel(const float* __restrict__ x,
                                                   float* __restrict__ pooled) {
    const int row  = blockIdx.x * 4 + (threadIdx.x >> 6);
    const int lane = threadIdx.x & 63;
    const float* r = x + (size_t)row * D_;
    float s = 0.f;
    if (lane < 48) {
        const float4 v = ((const float4*)r)[lane];
        s = v.x + v.y + v.z + v.w;
    }
#pragma unroll
    for (int off = 32; off > 0; off >>= 1) s += __shfl_down(s, off);
    if (lane == 0) pooled[row] = s * (1.f / 192.f);
}

// ---------------------------------------------------------------------------
// Kernel 2: per-sample kmeans — R5 PASS structure, only block size 256 -> 512
// (4 channels/thread in Phase A instead of 8; Phase B identical t<192 sweep).
// All FP chain orders bit-identical to R5.
// ---------------------------------------------------------------------------
__global__ __launch_bounds__(512) void kmeans_kernel(const float* __restrict__ x,
                                                     unsigned char* __restrict__ ids_out) {
    const int b = blockIdx.x, t = threadIdx.x;
    const int lane = t & 63;
    const float* X = x + (size_t)b * (C_ * (size_t)D_);

    __shared__ __align__(16) float cent[4][192];
    __shared__ float xs_s[C_];
    __shared__ float cs4[4];
    __shared__ int   cnt[4];
    __shared__ int   changed;
    __shared__ unsigned char ids[C_];

    if (t < 192) {
        cent[0][t] = X[(size_t)0    * D_ + t];
        cent[1][t] = X[(size_t)512  * D_ + t];
        cent[2][t] = X[(size_t)1024 * D_ + t];
        cent[3][t] = X[(size_t)1536 * D_ + t];
    }
    for (int c = t; c < C_; c += 512) {
        const float4* r4 = (const float4*)(X + (size_t)c * D_);
        xs_s[c] = pw96_sq_f4(r4) + pw96_sq_f4(r4 + 24);
        ids[c]  = 255;
    }
    __syncthreads();

    for (int iter = 0;; ++iter) {
        if (t < 4) {
            cs4[t] = pw96_sq_s(cent[t]) + pw96_sq_s(cent[t] + 96);
            cnt[t] = 0;
        }
        if (t == 0) changed = 0;
        __syncthreads();

        const float q0 = cs4[0], q1 = cs4[1], q2 = cs4[2], q3 = cs4[3];

        // ---- Phase A: 4 channels/thread, R5's sequential per-channel loop ----
        int lc0 = 0, lc1 = 0, lc2 = 0, lc3 = 0, mych = 0;
        for (int j = 0; j < 4; ++j) {
            const int c = t + 512 * j;
            const float4* r4 = (const float4*)(X + (size_t)c * D_);
            float d0 = 0.f, d1 = 0.f, d2 = 0.f, d3 = 0.f;
#pragma unroll 8
            for (int i = 0; i < 48; ++i) {
                const float4 a  = r4[i];
                const float4 c0 = *(const float4*)&cent[0][4 * i];
                const float4 c1 = *(const float4*)&cent[1][4 * i];
                const float4 c2 = *(const float4*)&cent[2][4 * i];
                const float4 c3 = *(const float4*)&cent[3][4 * i];
                d0 = fmaf(a.x, c0.x, d0); d0 = fmaf(a.y, c0.y, d0);
                d0 = fmaf(a.z, c0.z, d0); d0 = fmaf(a.w, c0.w, d0);
                d1 = fmaf(a.x, c1.x, d1); d1 = fmaf(a.y, c1.y, d1);
                d1 = fmaf(a.z, c1.z, d1); d1 = fmaf(a.w, c1.w, d1);
                d2 = fmaf(a.x, c2.x, d2); d2 = fmaf(a.y, c2.y, d2);
                d2 = fmaf(a.z, c2.z, d2); d2 = fmaf(a.w, c2.w, d2);
                d3 = fmaf(a.x, c3.x, d3); d3 = fmaf(a.y, c3.y, d3);
                d3 = fmaf(a.z, c3.z, d3); d3 = fmaf(a.w, c3.w, d3);
            }
            const float xv = xs_s[c];
            const float e0 = (xv - 2.0f * d0) + q0;
            const float e1 = (xv - 2.0f * d1) + q1;
            const float e2 = (xv - 2.0f * d2) + q2;
            const float e3 = (xv - 2.0f * d3) + q3;
            int id = 0; float best = e0;
            if (e1 < best) { best = e1; id = 1; }
            if (e2 < best) { best = e2; id = 2; }
            if (e3 < best) { best = e3; id = 3; }
            lc0 += (id == 0); lc1 += (id == 1); lc2 += (id == 2); lc3 += (id == 3);
            mych |= (ids[c] != (unsigned char)id);
            ids[c] = (unsigned char)id;
        }
#pragma unroll
        for (int off = 32; off > 0; off >>= 1) {
            lc0 += __shfl_down(lc0, off);
            lc1 += __shfl_down(lc1, off);
            lc2 += __shfl_down(lc2, off);
            lc3 += __shfl_down(lc3, off);
        }
        if (lane == 0) {
            atomicAdd(&cnt[0], lc0); atomicAdd(&cnt[1], lc1);
            atomicAdd(&cnt[2], lc2); atomicAdd(&cnt[3], lc3);
        }
        if (mych) changed = 1;
        __syncthreads();

        if (changed == 0 || iter == 10) break;   // converged -> exact fixed point

        // ---- Phase B: exact R5 version. Thread t owns dim d=t; ascending c
        // within Q=384 K-blocks, blocks combined sequentially. ----
        if (t < 192) {
            float t0 = 0.f, t1 = 0.f, t2 = 0.f, t3 = 0.f;
            for (int kb = 0; kb < C_; kb += BLAS_Q) {
                const int ke = (kb + BLAS_Q < C_) ? (kb + BLAS_Q) : C_;
                float s0 = 0.f, s1 = 0.f, s2 = 0.f, s3 = 0.f;
                for (int c = kb; c < ke; ++c) {
                    const float xv = X[(size_t)c * D_ + t];
                    const int id = ids[c];
                    s0 += (id == 0) ? xv : 0.0f;
                    s1 += (id == 1) ? xv : 0.0f;
                    s2 += (id == 2) ? xv : 0.0f;
                    s3 += (id == 3) ? xv : 0.0f;
                }
                t0 += s0; t1 += s1; t2 += s2; t3 += s3;
            }
            if (cnt[0] > 0) cent[0][t] = t0 / (float)cnt[0];
            if (cnt[1] > 0) cent[1][t] = t1 / (float)cnt[1];
            if (cnt[2] > 0) cent[2][t] = t2 / (float)cnt[2];
            if (cnt[3] > 0) cent[3][t] = t3 / (float)cnt[3];
        }
        __syncthreads();
    }

    for (int c = t; c < C_; c += 512) ids_out[(size_t)b * C_ + c] = ids[c];
}

// ---------------------------------------------------------------------------
__device__ __forceinline__ float bn_apply(float v, float g, float be, float m, float va) {
    return (v - m) / sqrtf(va + EPSf) * g + be;
}

// ---------------------------------------------------------------------------
// Kernel 3: batched 64x64-tiled GEMM, M=256, N=512, K=2048.
//  z==0: xg2 = bn2(relu(bn1(pooled@Wg^T + bg)))
//  z>=1: h1[k] = relu(bn(n1, maskedpooled@W1^T + b1)), mask = (ids==k)
// ---------------------------------------------------------------------------
__global__ __launch_bounds__(256) void gemm1_kernel(
    const float* __restrict__ pooled, const unsigned char* __restrict__ ids,
    const float* __restrict__ Wg, const float* __restrict__ bg,
    const float* __restrict__ g_gamma, const float* __restrict__ g_beta,
    const float* __restrict__ g_mean, const float* __restrict__ g_var,
    const float* __restrict__ gb_gamma, const float* __restrict__ gb_beta,
    const float* __restrict__ gb_mean, const float* __restrict__ gb_var,
    const float* __restrict__ W1, const float* __restrict__ b1,
    const float* __restrict__ n1_gamma, const float* __restrict__ n1_beta,
    const float* __restrict__ n1_mean, const float* __restrict__ n1_var,
    float* __restrict__ xg2, float* __restrict__ h1) {
    const int z = blockIdx.z;
    const int bn0 = blockIdx.x * 64, bm0 = blockIdx.y * 64;
    const float* Bmat = (z == 0) ? Wg : W1;
    __shared__ float As[32][68];
    __shared__ float Bs[32][68];
    float acc[4][4] = {};
    const int t = threadIdx.x;
    const int tx = t & 15, ty = t >> 4;

    for (int k0 = 0; k0 < 2048; k0 += 32) {
#pragma unroll
        for (int u = 0; u < 2; ++u) {
            const int idx = t + 256 * u;
            const int m = idx >> 3, kc = idx & 7;
            float4 v = *(const float4*)(pooled + (size_t)(bm0 + m) * 2048 + k0 + kc * 4);
            if (z > 0) {
                const unsigned int uu =
                    *(const unsigned int*)(ids + (size_t)(bm0 + m) * 2048 + k0 + kc * 4);
                const unsigned int k = (unsigned int)(z - 1);
                v.x = ((uu & 0xffu) == k) ? v.x : 0.f;
                v.y = (((uu >> 8) & 0xffu) == k) ? v.y : 0.f;
                v.z = (((uu >> 16) & 0xffu) == k) ? v.z : 0.f;
                v.w = (((uu >> 24) & 0xffu) == k) ? v.w : 0.f;
            }
            As[kc * 4 + 0][m] = v.x; As[kc * 4 + 1][m] = v.y;
            As[kc * 4 + 2][m] = v.z; As[kc * 4 + 3][m] = v.w;
            const float4 wv = *(const float4*)(Bmat + (size_t)(bn0 + m) * 2048 + k0 + kc * 4);
            Bs[kc * 4 + 0][m] = wv.x; Bs[kc * 4 + 1][m] = wv.y;
            Bs[kc * 4 + 2][m] = wv.z; Bs[kc * 4 + 3][m] = wv.w;
        }
        __syncthreads();
#pragma unroll 8
        for (int kk = 0; kk < 32; ++kk) {
            const float4 a = *(const float4*)&As[kk][ty * 4];
            const float4 wv = *(const float4*)&Bs[kk][tx * 4];
            const float av[4] = {a.x, a.y, a.z, a.w};
            const float bv[4] = {wv.x, wv.y, wv.z, wv.w};
#pragma unroll
            for (int i = 0; i < 4; ++i)
#pragma unroll
                for (int j = 0; j < 4; ++j) acc[i][j] += av[i] * bv[j];
        }
        __syncthreads();
    }

    const int m0 = bm0 + ty * 4, n0 = bn0 + tx * 4;
    if (z == 0) {
#pragma unroll
        for (int j = 0; j < 4; ++j) {
            const int n = n0 + j;
            const float bgv = bg[n];
            const float g1 = g_gamma[n], be1 = g_beta[n], mm1 = g_mean[n], vv1 = g_var[n];
            const float g2 = gb_gamma[n], be2 = gb_beta[n], mm2 = gb_mean[n], vv2 = gb_var[n];
#pragma unroll
            for (int i = 0; i < 4; ++i) {
                float v = acc[i][j] + bgv;
                v = bn_apply(v, g1, be1, mm1, vv1);
                v = fmaxf(v, 0.f);
                v = bn_apply(v, g2, be2, mm2, vv2);
                xg2[(size_t)(m0 + i) * 512 + n] = v;
            }
        }
    } else {
        const int k = z - 1;
#pragma unroll
        for (int j = 0; j < 4; ++j) {
            const int n = n0 + j;
            const float b1v = b1[n];
            const float g1 = n1_gamma[n], be1 = n1_beta[n], mm1 = n1_mean[n], vv1 = n1_var[n];
#pragma unroll
            for (int i = 0; i < 4; ++i) {
                float v = acc[i][j] + b1v;
                v = bn_apply(v, g1, be1, mm1, vv1);
                v = fmaxf(v, 0.f);
                h1[((size_t)k * 256 + (m0 + i)) * 512 + n] = v;
            }
        }
    }
}

// ---------------------------------------------------------------------------
// Kernel 4: h2 = relu(bn(n2, h1@W2^T + b2)); then per-branch bk BN;
// write y[b, k*128+p]. M=1024 (k*256+b), N=128, K=512.
// ---------------------------------------------------------------------------
__global__ __launch_bounds__(256) void gemm2_kernel(
    const float* __restrict__ h1, const float* __restrict__ W2,
    const float* __restrict__ b2,
    const float* __restrict__ n2_gamma, const float* __restrict__ n2_beta,
    const float* __restrict__ n2_mean, const float* __restrict__ n2_var,
    const float* __restrict__ bk_gamma, const float* __restrict__ bk_beta,
    const float* __restrict__ bk_mean, const float* __restrict__ bk_var,
    float* __restrict__ yv) {
    const int bn0 = blockIdx.x * 64, bm0 = blockIdx.y * 64;
    __shared__ float As[32][68];
    __shared__ float Bs[32][68];
    float acc[4][4] = {};
    const int t = threadIdx.x;
    const int tx = t & 15, ty = t >> 4;

    for (int k0 = 0; k0 < 512; k0 += 32) {
#pragma unroll
        for (int u = 0; u < 2; ++u) {
            const int idx = t + 256 * u;
            const int m = idx >> 3, kc = idx & 7;
            const float4 v = *(const float4*)(h1 + (size_t)(bm0 + m) * 512 + k0 + kc * 4);
            As[kc * 4 + 0][m] = v.x; As[kc * 4 + 1][m] = v.y;
            As[kc * 4 + 2][m] = v.z; As[kc * 4 + 3][m] = v.w;
            const float4 wv = *(const float4*)(W2 + (size_t)(bn0 + m) * 512 + k0 + kc * 4);
            Bs[kc * 4 + 0][m] = wv.x; Bs[kc * 4 + 1][m] = wv.y;
            Bs[kc * 4 + 2][m] = wv.z; Bs[kc * 4 + 3][m] = wv.w;
        }
        __syncthreads();
#pragma unroll 8
        for (int kk = 0; kk < 32; ++kk) {
            const float4 a = *(const float4*)&As[kk][ty * 4];
            const float4 wv = *(const float4*)&Bs[kk][tx * 4];
            const float av[4] = {a.x, a.y, a.z, a.w};
            const float bv[4] = {wv.x, wv.y, wv.z, wv.w};
#pragma unroll
            for (int i = 0; i < 4; ++i)
#pragma unroll
                for (int j = 0; j < 4; ++j) acc[i][j] += av[i] * bv[j];
        }
        __syncthreads();
    }

    const int m0 = bm0 + ty * 4, n0 = bn0 + tx * 4;
#pragma unroll
    for (int j = 0; j < 4; ++j) {
        const int n = n0 + j;
        const float b2v = b2[n];
        const float g1 = n2_gamma[n], be1 = n2_beta[n], mm1 = n2_mean[n], vv1 = n2_var[n];
#pragma unroll
        for (int i = 0; i < 4; ++i) {
            const int row = m0 + i;
            const int k = row >> 8, b = row & 255;
            float v = acc[i][j] + b2v;
            v = bn_apply(v, g1, be1, mm1, vv1);
            v = fmaxf(v, 0.f);
            const int pi = k * 128 + n;
            v = bn_apply(v, bk_gamma[pi], bk_beta[pi], bk_mean[pi], bk_var[pi]);
            yv[(size_t)b * 512 + pi] = v;
        }
    }
}

// ---------------------------------------------------------------------------
// Kernel 5: heads. x_pre = xg2@Wcg^T + bcg ; y_pre = y@Wck^T + bck
// ---------------------------------------------------------------------------
__global__ __launch_bounds__(128) void head_kernel(
    const float* __restrict__ xg2, const float* __restrict__ yv,
    const float* __restrict__ Wcg, const float* __restrict__ bcg,
    const float* __restrict__ Wck, const float* __restrict__ bck,
    float* __restrict__ out) {
    const int b = blockIdx.x, t = threadIdx.x;
    __shared__ float xr[512], yr[512];
    ((float4*)xr)[t] = ((const float4*)(xg2 + (size_t)b * 512))[t];
    ((float4*)yr)[t] = ((const float4*)(yv + (size_t)b * 512))[t];
    __syncthreads();
    if (t < 51) {
        float acc = 0.f;
        const float4* wr = (const float4*)(Wcg + (size_t)t * 512);
        const float4* xv = (const float4*)xr;
#pragma unroll 8
        for (int p = 0; p < 128; ++p) {
            const float4 w4 = wr[p], v4 = xv[p];
            acc += w4.x * v4.x + w4.y * v4.y + w4.z * v4.z + w4.w * v4.w;
        }
        out[(size_t)b * 51 + t] = acc + bcg[t];
    } else if (t >= 64 && t < 115) {
        const int n = t - 64;
        float acc = 0.f;
        const float4* wr = (const float4*)(Wck + (size_t)n * 512);
        const float4* yv4 = (const float4*)yr;
#pragma unroll 8
        for (int p = 0; p < 128; ++p) {
            const float4 w4 = wr[p], v4 = yv4[p];
            acc += w4.x * v4.x + w4.y * v4.y + w4.z * v4.z + w4.w * v4.w;
        }
        out[(size_t)(B_ * 51) + (size_t)b * 51 + n] = acc + bck[n];
    }
}

// ---------------------------------------------------------------------------
extern "C" void kernel_launch(void* const* d_in, const int* in_sizes, int n_in,
                              void* d_out, int out_size, void* d_ws, size_t ws_size,
                              hipStream_t stream) {
    const float* x        = (const float*)d_in[0];
    const float* Wg       = (const float*)d_in[1];
    const float* bg       = (const float*)d_in[2];
    const float* g_gamma  = (const float*)d_in[3];
    const float* g_beta   = (const float*)d_in[4];
    const float* g_mean   = (const float*)d_in[5];
    const float* g_var    = (const float*)d_in[6];
    const float* gb_gamma = (const float*)d_in[7];
    const float* gb_beta  = (const float*)d_in[8];
    const float* gb_mean  = (const float*)d_in[9];
    const float* gb_var   = (const float*)d_in[10];
    const float* Wcg      = (const float*)d_in[11];
    const float* bcg      = (const float*)d_in[12];
    const float* W1       = (const float*)d_in[13];
    const float* b1       = (const float*)d_in[14];
    const float* n1_gamma = (const float*)d_in[15];
    const float* n1_beta  = (const float*)d_in[16];
    const float* n1_mean  = (const float*)d_in[17];
    const float* n1_var   = (const float*)d_in[18];
    const float* W2       = (const float*)d_in[19];
    const float* b2       = (const float*)d_in[20];
    const float* n2_gamma = (const float*)d_in[21];
    const float* n2_beta  = (const float*)d_in[22];
    const float* n2_mean  = (const float*)d_in[23];
    const float* n2_var   = (const float*)d_in[24];
    const float* bk_gamma = (const float*)d_in[25];
    const float* bk_beta  = (const float*)d_in[26];
    const float* bk_mean  = (const float*)d_in[27];
    const float* bk_var   = (const float*)d_in[28];
    const float* Wck      = (const float*)d_in[29];
    const float* bck      = (const float*)d_in[30];
    float* out = (float*)d_out;

    float* pooled      = (float*)d_ws;                       // 524288 f
    unsigned char* ids = (unsigned char*)(pooled + 524288);  // 524288 B
    float* xg2         = (float*)(ids + 524288);             // 131072 f
    float* h1          = xg2 + 131072;                       // 524288 f
    float* yv          = h1 + 524288;                        // 131072 f

    pool_kernel<<<dim3((B_ * C_) / 4), dim3(256), 0, stream>>>(x, pooled);
    kmeans_kernel<<<dim3(B_), dim3(512), 0, stream>>>(x, ids);
    gemm1_kernel<<<dim3(8, 4, 5), dim3(256), 0, stream>>>(
        pooled, ids, Wg, bg, g_gamma, g_beta, g_mean, g_var,
        gb_gamma, gb_beta, gb_mean, gb_var, W1, b1,
        n1_gamma, n1_beta, n1_mean, n1_var, xg2, h1);
    gemm2_kernel<<<dim3(2, 16), dim3(256), 0, stream>>>(
        h1, W2, b2, n2_gamma, n2_beta, n2_mean, n2_var,
        bk_gamma, bk_beta, bk_mean, bk_var, yv);
    head_kernel<<<dim3(B_), dim3(128), 0, stream>>>(xg2, yv, Wcg, bcg, Wck, bck, out);
}

// Round 10
// 3517.966 us; speedup vs baseline: 1.1276x; 1.0710x over previous
//
#include <hip/hip_runtime.h>
#include <math.h>

#define B_   256
#define C_   2048
#define D_   192
#define EPSf 1e-5f
#define BLAS_Q 384   // OpenBLAS SGEMM_DEFAULT_Q — K-block size (validated in R5)

// ---------------------------------------------------------------------------
// numpy pairwise helpers (validated bit-exact in R5/R8).
// ---------------------------------------------------------------------------
__device__ __forceinline__ float pw96_sq_f4(const float4* a4) {
    float r0 = 0.f, r1 = 0.f, r2 = 0.f, r3 = 0.f, r4 = 0.f, r5 = 0.f, r6 = 0.f, r7 = 0.f;
#pragma unroll
    for (int i = 0; i < 12; ++i) {
        const float4 v0 = a4[2 * i], v1 = a4[2 * i + 1];
        r0 += __fmul_rn(v0.x, v0.x); r1 += __fmul_rn(v0.y, v0.y);
        r2 += __fmul_rn(v0.z, v0.z); r3 += __fmul_rn(v0.w, v0.w);
        r4 += __fmul_rn(v1.x, v1.x); r5 += __fmul_rn(v1.y, v1.y);
        r6 += __fmul_rn(v1.z, v1.z); r7 += __fmul_rn(v1.w, v1.w);
    }
    return ((r0 + r1) + (r2 + r3)) + ((r4 + r5) + (r6 + r7));
}

__device__ __forceinline__ float pw96_sq_s(const float* a) {
    float r0 = 0.f, r1 = 0.f, r2 = 0.f, r3 = 0.f, r4 = 0.f, r5 = 0.f, r6 = 0.f, r7 = 0.f;
#pragma unroll
    for (int i = 0; i < 12; ++i) {
        r0 += __fmul_rn(a[8 * i + 0], a[8 * i + 0]);
        r1 += __fmul_rn(a[8 * i + 1], a[8 * i + 1]);
        r2 += __fmul_rn(a[8 * i + 2], a[8 * i + 2]);
        r3 += __fmul_rn(a[8 * i + 3], a[8 * i + 3]);
        r4 += __fmul_rn(a[8 * i + 4], a[8 * i + 4]);
        r5 += __fmul_rn(a[8 * i + 5], a[8 * i + 5]);
        r6 += __fmul_rn(a[8 * i + 6], a[8 * i + 6]);
        r7 += __fmul_rn(a[8 * i + 7], a[8 * i + 7]);
    }
    return ((r0 + r1) + (r2 + r3)) + ((r4 + r5) + (r6 + r7));
}

// ---------------------------------------------------------------------------
// Kernel 0 (fast path): tile-transpose x[b][c][d] -> xT[b][d][c].
// Both global accesses coalesced (256B per wave); LDS 64x65 breaks conflicts.
// ---------------------------------------------------------------------------
__global__ __launch_bounds__(256) void transpose_kernel(const float* __restrict__ x,
                                                        float* __restrict__ xT) {
    const int b = blockIdx.z, c0 = blockIdx.x * 64, d0 = blockIdx.y * 64;
    const float* X = x + (size_t)b * (C_ * (size_t)D_);
    float* XT      = xT + (size_t)b * (C_ * (size_t)D_);
    __shared__ float tile[64][65];
    const int tx = threadIdx.x & 63, ty = threadIdx.x >> 6;
#pragma unroll
    for (int i = 0; i < 16; ++i) {
        const int c = ty + i * 4;
        tile[c][tx] = X[(size_t)(c0 + c) * D_ + d0 + tx];
    }
    __syncthreads();
#pragma unroll
    for (int i = 0; i < 16; ++i) {
        const int d = ty + i * 4;
        XT[(size_t)(d0 + d) * C_ + c0 + tx] = tile[tx][d];
    }
}

// ---------------------------------------------------------------------------
// Kernel 1 (fast path): fused pool + kmeans, 1024 thr/block, 1 block/sample.
// Phase A + init read xT (coalesced: lanes = consecutive channels);
// Phase B reads original x (coalesced: lanes = consecutive dims), task-
// parallel over (kb, d) WITH the c<2048 clamp (R6/R7 bug fixed).
// All per-chain FP orders bit-identical to the R5/R8 PASS.
// ---------------------------------------------------------------------------
__global__ __launch_bounds__(1024) void kmeans_fast_kernel(const float* __restrict__ x,
                                                           const float* __restrict__ xT,
                                                           float* __restrict__ pooled,
                                                           unsigned char* __restrict__ ids_out) {
    const int b = blockIdx.x, t = threadIdx.x;
    const int lane = t & 63;
    const float* X   = x  + (size_t)b * (C_ * (size_t)D_);
    const float* XTb = xT + (size_t)b * (C_ * (size_t)D_);

    __shared__ __align__(16) float cent[4][192];
    __shared__ float xs_s[C_];
    __shared__ float part[6][4][192];
    __shared__ float cs4[4];
    __shared__ int   cnt[4];
    __shared__ int   changed;
    __shared__ unsigned char ids[C_];

    if (t < 192) {
        cent[0][t] = X[(size_t)0    * D_ + t];
        cent[1][t] = X[(size_t)512  * D_ + t];
        cent[2][t] = X[(size_t)1024 * D_ + t];
        cent[3][t] = X[(size_t)1536 * D_ + t];
    }
    // init: xs (np pairwise 96+96, 8 accums) + pooled, coalesced from xT
#pragma unroll
    for (int j = 0; j < 2; ++j) {
        const int c = t + 1024 * j;
        float sqv = 0.f, smv = 0.f;
#pragma unroll
        for (int blk = 0; blk < 2; ++blk) {
            float q[8], s[8];
#pragma unroll
            for (int jj = 0; jj < 8; ++jj) { q[jj] = 0.f; s[jj] = 0.f; }
#pragma unroll
            for (int i = 0; i < 12; ++i) {
#pragma unroll
                for (int jj = 0; jj < 8; ++jj) {
                    const float v = XTb[(size_t)(blk * 96 + 8 * i + jj) * C_ + c];
                    q[jj] += __fmul_rn(v, v);
                    s[jj] += v;
                }
            }
            sqv += ((q[0] + q[1]) + (q[2] + q[3])) + ((q[4] + q[5]) + (q[6] + q[7]));
            smv += ((s[0] + s[1]) + (s[2] + s[3])) + ((s[4] + s[5]) + (s[6] + s[7]));
        }
        xs_s[c] = sqv;
        pooled[(size_t)b * C_ + c] = smv / 192.0f;
        ids[c] = 255;
    }
    __syncthreads();

    for (int iter = 0;; ++iter) {
        if (t < 4) {
            cs4[t] = pw96_sq_s(cent[t]) + pw96_sq_s(cent[t] + 96);
            cnt[t] = 0;
        }
        if (t == 0) changed = 0;
        __syncthreads();

        const float q0 = cs4[0], q1 = cs4[1], q2 = cs4[2], q3 = cs4[3];

        // ---- Phase A: 2 channels/thread, coalesced scalar reads from xT;
        // each (channel,k) chain ascends d=0..191 sequentially (R5 order). ----
        int lc0 = 0, lc1 = 0, lc2 = 0, lc3 = 0, mych = 0;
        {
            const int cA = t, cB = t + 1024;
            float dA0 = 0.f, dA1 = 0.f, dA2 = 0.f, dA3 = 0.f;
            float dB0 = 0.f, dB1 = 0.f, dB2 = 0.f, dB3 = 0.f;
#pragma unroll 8
            for (int d = 0; d < 192; ++d) {
                const float a  = XTb[(size_t)d * C_ + cA];
                const float bb = XTb[(size_t)d * C_ + cB];
                const float c0 = cent[0][d], c1 = cent[1][d];
                const float c2 = cent[2][d], c3 = cent[3][d];
                dA0 = fmaf(a, c0, dA0);  dA1 = fmaf(a, c1, dA1);
                dA2 = fmaf(a, c2, dA2);  dA3 = fmaf(a, c3, dA3);
                dB0 = fmaf(bb, c0, dB0); dB1 = fmaf(bb, c1, dB1);
                dB2 = fmaf(bb, c2, dB2); dB3 = fmaf(bb, c3, dB3);
            }
            {
                const float xv = xs_s[cA];
                const float e0 = (xv - 2.0f * dA0) + q0;
                const float e1 = (xv - 2.0f * dA1) + q1;
                const float e2 = (xv - 2.0f * dA2) + q2;
                const float e3 = (xv - 2.0f * dA3) + q3;
                int id = 0; float best = e0;
                if (e1 < best) { best = e1; id = 1; }
                if (e2 < best) { best = e2; id = 2; }
                if (e3 < best) { best = e3; id = 3; }
                lc0 += (id == 0); lc1 += (id == 1); lc2 += (id == 2); lc3 += (id == 3);
                mych |= (ids[cA] != (unsigned char)id);
                ids[cA] = (unsigned char)id;
            }
            {
                const float xv = xs_s[cB];
                const float e0 = (xv - 2.0f * dB0) + q0;
                const float e1 = (xv - 2.0f * dB1) + q1;
                const float e2 = (xv - 2.0f * dB2) + q2;
                const float e3 = (xv - 2.0f * dB3) + q3;
                int id = 0; float best = e0;
                if (e1 < best) { best = e1; id = 1; }
                if (e2 < best) { best = e2; id = 2; }
                if (e3 < best) { best = e3; id = 3; }
                lc0 += (id == 0); lc1 += (id == 1); lc2 += (id == 2); lc3 += (id == 3);
                mych |= (ids[cB] != (unsigned char)id);
                ids[cB] = (unsigned char)id;
            }
        }
#pragma unroll
        for (int off = 32; off > 0; off >>= 1) {
            lc0 += __shfl_down(lc0, off);
            lc1 += __shfl_down(lc1, off);
            lc2 += __shfl_down(lc2, off);
            lc3 += __shfl_down(lc3, off);
        }
        if (lane == 0) {
            atomicAdd(&cnt[0], lc0); atomicAdd(&cnt[1], lc1);
            atomicAdd(&cnt[2], lc2); atomicAdd(&cnt[3], lc3);
        }
        if (mych) changed = 1;
        __syncthreads();

        if (changed == 0 || iter == 10) break;   // converged -> exact fixed point

        // ---- Phase B: 1152 tasks (kb, d), CLAMPED to 2048 channels.
        // Waves never straddle kb (192 = 3*64); lanes read consecutive d. ----
        for (int task = t; task < 1152; task += 1024) {
            const int kb = task / 192;
            const int d  = task - kb * 192;
            const int cb = kb * BLAS_Q;
            const int ce = (cb + BLAS_Q < C_) ? (cb + BLAS_Q) : C_;   // the fix
            float s0 = 0.f, s1 = 0.f, s2 = 0.f, s3 = 0.f;
            for (int c = cb; c < ce; ++c) {
                const float xv = X[(size_t)c * D_ + d];
                const int id = ids[c];
                s0 += (id == 0) ? xv : 0.0f;
                s1 += (id == 1) ? xv : 0.0f;
                s2 += (id == 2) ? xv : 0.0f;
                s3 += (id == 3) ? xv : 0.0f;
            }
            part[kb][0][d] = s0; part[kb][1][d] = s1;
            part[kb][2][d] = s2; part[kb][3][d] = s3;
        }
        __syncthreads();
        if (t < 192) {
#pragma unroll
            for (int k = 0; k < 4; ++k) {
                float tt = part[0][k][t];          // = 0 + p0 exactly (R5 order)
                tt += part[1][k][t];
                tt += part[2][k][t];
                tt += part[3][k][t];
                tt += part[4][k][t];
                tt += part[5][k][t];
                if (cnt[k] > 0) cent[k][t] = tt / (float)cnt[k];
            }
        }
        __syncthreads();
    }

#pragma unroll
    for (int j = 0; j < 2; ++j) {
        const int c = t + 1024 * j;
        ids_out[(size_t)b * C_ + c] = ids[c];
    }
}

// ---------------------------------------------------------------------------
// FALLBACK (ws too small): exact R8 PASS kernels.
// ---------------------------------------------------------------------------
__global__ __launch_bounds__(256) void pool_kernel(const float* __restrict__ x,
                                                   float* __restrict__ pooled) {
    const int row  = blockIdx.x * 4 + (threadIdx.x >> 6);
    const int lane = threadIdx.x & 63;
    const float* r = x + (size_t)row * D_;
    float s = 0.f;
    if (lane < 48) {
        const float4 v = ((const float4*)r)[lane];
        s = v.x + v.y + v.z + v.w;
    }
#pragma unroll
    for (int off = 32; off > 0; off >>= 1) s += __shfl_down(s, off);
    if (lane == 0) pooled[row] = s * (1.f / 192.f);
}

__global__ __launch_bounds__(512) void kmeans_fb_kernel(const float* __restrict__ x,
                                                        unsigned char* __restrict__ ids_out) {
    const int b = blockIdx.x, t = threadIdx.x;
    const int lane = t & 63;
    const float* X = x + (size_t)b * (C_ * (size_t)D_);

    __shared__ __align__(16) float cent[4][192];
    __shared__ float xs_s[C_];
    __shared__ float cs4[4];
    __shared__ int   cnt[4];
    __shared__ int   changed;
    __shared__ unsigned char ids[C_];

    if (t < 192) {
        cent[0][t] = X[(size_t)0    * D_ + t];
        cent[1][t] = X[(size_t)512  * D_ + t];
        cent[2][t] = X[(size_t)1024 * D_ + t];
        cent[3][t] = X[(size_t)1536 * D_ + t];
    }
    for (int c = t; c < C_; c += 512) {
        const float4* r4 = (const float4*)(X + (size_t)c * D_);
        xs_s[c] = pw96_sq_f4(r4) + pw96_sq_f4(r4 + 24);
        ids[c]  = 255;
    }
    __syncthreads();

    for (int iter = 0;; ++iter) {
        if (t < 4) {
            cs4[t] = pw96_sq_s(cent[t]) + pw96_sq_s(cent[t] + 96);
            cnt[t] = 0;
        }
        if (t == 0) changed = 0;
        __syncthreads();

        const float q0 = cs4[0], q1 = cs4[1], q2 = cs4[2], q3 = cs4[3];
        int lc0 = 0, lc1 = 0, lc2 = 0, lc3 = 0, mych = 0;
        for (int j = 0; j < 4; ++j) {
            const int c = t + 512 * j;
            const float4* r4 = (const float4*)(X + (size_t)c * D_);
            float d0 = 0.f, d1 = 0.f, d2 = 0.f, d3 = 0.f;
#pragma unroll 8
            for (int i = 0; i < 48; ++i) {
                const float4 a  = r4[i];
                const float4 c0 = *(const float4*)&cent[0][4 * i];
                const float4 c1 = *(const float4*)&cent[1][4 * i];
                const float4 c2 = *(const float4*)&cent[2][4 * i];
                const float4 c3 = *(const float4*)&cent[3][4 * i];
                d0 = fmaf(a.x, c0.x, d0); d0 = fmaf(a.y, c0.y, d0);
                d0 = fmaf(a.z, c0.z, d0); d0 = fmaf(a.w, c0.w, d0);
                d1 = fmaf(a.x, c1.x, d1); d1 = fmaf(a.y, c1.y, d1);
                d1 = fmaf(a.z, c1.z, d1); d1 = fmaf(a.w, c1.w, d1);
                d2 = fmaf(a.x, c2.x, d2); d2 = fmaf(a.y, c2.y, d2);
                d2 = fmaf(a.z, c2.z, d2); d2 = fmaf(a.w, c2.w, d2);
                d3 = fmaf(a.x, c3.x, d3); d3 = fmaf(a.y, c3.y, d3);
                d3 = fmaf(a.z, c3.z, d3); d3 = fmaf(a.w, c3.w, d3);
            }
            const float xv = xs_s[c];
            const float e0 = (xv - 2.0f * d0) + q0;
            const float e1 = (xv - 2.0f * d1) + q1;
            const float e2 = (xv - 2.0f * d2) + q2;
            const float e3 = (xv - 2.0f * d3) + q3;
            int id = 0; float best = e0;
            if (e1 < best) { best = e1; id = 1; }
            if (e2 < best) { best = e2; id = 2; }
            if (e3 < best) { best = e3; id = 3; }
            lc0 += (id == 0); lc1 += (id == 1); lc2 += (id == 2); lc3 += (id == 3);
            mych |= (ids[c] != (unsigned char)id);
            ids[c] = (unsigned char)id;
        }
#pragma unroll
        for (int off = 32; off > 0; off >>= 1) {
            lc0 += __shfl_down(lc0, off);
            lc1 += __shfl_down(lc1, off);
            lc2 += __shfl_down(lc2, off);
            lc3 += __shfl_down(lc3, off);
        }
        if (lane == 0) {
            atomicAdd(&cnt[0], lc0); atomicAdd(&cnt[1], lc1);
            atomicAdd(&cnt[2], lc2); atomicAdd(&cnt[3], lc3);
        }
        if (mych) changed = 1;
        __syncthreads();

        if (changed == 0 || iter == 10) break;

        if (t < 192) {
            float t0 = 0.f, t1 = 0.f, t2 = 0.f, t3 = 0.f;
            for (int kb = 0; kb < C_; kb += BLAS_Q) {
                const int ke = (kb + BLAS_Q < C_) ? (kb + BLAS_Q) : C_;
                float s0 = 0.f, s1 = 0.f, s2 = 0.f, s3 = 0.f;
                for (int c = kb; c < ke; ++c) {
                    const float xv = X[(size_t)c * D_ + t];
                    const int id = ids[c];
                    s0 += (id == 0) ? xv : 0.0f;
                    s1 += (id == 1) ? xv : 0.0f;
                    s2 += (id == 2) ? xv : 0.0f;
                    s3 += (id == 3) ? xv : 0.0f;
                }
                t0 += s0; t1 += s1; t2 += s2; t3 += s3;
            }
            if (cnt[0] > 0) cent[0][t] = t0 / (float)cnt[0];
            if (cnt[1] > 0) cent[1][t] = t1 / (float)cnt[1];
            if (cnt[2] > 0) cent[2][t] = t2 / (float)cnt[2];
            if (cnt[3] > 0) cent[3][t] = t3 / (float)cnt[3];
        }
        __syncthreads();
    }

    for (int c = t; c < C_; c += 512) ids_out[(size_t)b * C_ + c] = ids[c];
}

// ---------------------------------------------------------------------------
__device__ __forceinline__ float bn_apply(float v, float g, float be, float m, float va) {
    return (v - m) / sqrtf(va + EPSf) * g + be;
}

// ---------------------------------------------------------------------------
// Kernel 3: batched 64x64-tiled GEMM, M=256, N=512, K=2048.
// ---------------------------------------------------------------------------
__global__ __launch_bounds__(256) void gemm1_kernel(
    const float* __restrict__ pooled, const unsigned char* __restrict__ ids,
    const float* __restrict__ Wg, const float* __restrict__ bg,
    const float* __restrict__ g_gamma, const float* __restrict__ g_beta,
    const float* __restrict__ g_mean, const float* __restrict__ g_var,
    const float* __restrict__ gb_gamma, const float* __restrict__ gb_beta,
    const float* __restrict__ gb_mean, const float* __restrict__ gb_var,
    const float* __restrict__ W1, const float* __restrict__ b1,
    const float* __restrict__ n1_gamma, const float* __restrict__ n1_beta,
    const float* __restrict__ n1_mean, const float* __restrict__ n1_var,
    float* __restrict__ xg2, float* __restrict__ h1) {
    const int z = blockIdx.z;
    const int bn0 = blockIdx.x * 64, bm0 = blockIdx.y * 64;
    const float* Bmat = (z == 0) ? Wg : W1;
    __shared__ float As[32][68];
    __shared__ float Bs[32][68];
    float acc[4][4] = {};
    const int t = threadIdx.x;
    const int tx = t & 15, ty = t >> 4;

    for (int k0 = 0; k0 < 2048; k0 += 32) {
#pragma unroll
        for (int u = 0; u < 2; ++u) {
            const int idx = t + 256 * u;
            const int m = idx >> 3, kc = idx & 7;
            float4 v = *(const float4*)(pooled + (size_t)(bm0 + m) * 2048 + k0 + kc * 4);
            if (z > 0) {
                const unsigned int uu =
                    *(const unsigned int*)(ids + (size_t)(bm0 + m) * 2048 + k0 + kc * 4);
                const unsigned int k = (unsigned int)(z - 1);
                v.x = ((uu & 0xffu) == k) ? v.x : 0.f;
                v.y = (((uu >> 8) & 0xffu) == k) ? v.y : 0.f;
                v.z = (((uu >> 16) & 0xffu) == k) ? v.z : 0.f;
                v.w = (((uu >> 24) & 0xffu) == k) ? v.w : 0.f;
            }
            As[kc * 4 + 0][m] = v.x; As[kc * 4 + 1][m] = v.y;
            As[kc * 4 + 2][m] = v.z; As[kc * 4 + 3][m] = v.w;
            const float4 wv = *(const float4*)(Bmat + (size_t)(bn0 + m) * 2048 + k0 + kc * 4);
            Bs[kc * 4 + 0][m] = wv.x; Bs[kc * 4 + 1][m] = wv.y;
            Bs[kc * 4 + 2][m] = wv.z; Bs[kc * 4 + 3][m] = wv.w;
        }
        __syncthreads();
#pragma unroll 8
        for (int kk = 0; kk < 32; ++kk) {
            const float4 a = *(const float4*)&As[kk][ty * 4];
            const float4 wv = *(const float4*)&Bs[kk][tx * 4];
            const float av[4] = {a.x, a.y, a.z, a.w};
            const float bv[4] = {wv.x, wv.y, wv.z, wv.w};
#pragma unroll
            for (int i = 0; i < 4; ++i)
#pragma unroll
                for (int j = 0; j < 4; ++j) acc[i][j] += av[i] * bv[j];
        }
        __syncthreads();
    }

    const int m0 = bm0 + ty * 4, n0 = bn0 + tx * 4;
    if (z == 0) {
#pragma unroll
        for (int j = 0; j < 4; ++j) {
            const int n = n0 + j;
            const float bgv = bg[n];
            const float g1 = g_gamma[n], be1 = g_beta[n], mm1 = g_mean[n], vv1 = g_var[n];
            const float g2 = gb_gamma[n], be2 = gb_beta[n], mm2 = gb_mean[n], vv2 = gb_var[n];
#pragma unroll
            for (int i = 0; i < 4; ++i) {
                float v = acc[i][j] + bgv;
                v = bn_apply(v, g1, be1, mm1, vv1);
                v = fmaxf(v, 0.f);
                v = bn_apply(v, g2, be2, mm2, vv2);
                xg2[(size_t)(m0 + i) * 512 + n] = v;
            }
        }
    } else {
        const int k = z - 1;
#pragma unroll
        for (int j = 0; j < 4; ++j) {
            const int n = n0 + j;
            const float b1v = b1[n];
            const float g1 = n1_gamma[n], be1 = n1_beta[n], mm1 = n1_mean[n], vv1 = n1_var[n];
#pragma unroll
            for (int i = 0; i < 4; ++i) {
                float v = acc[i][j] + b1v;
                v = bn_apply(v, g1, be1, mm1, vv1);
                v = fmaxf(v, 0.f);
                h1[((size_t)k * 256 + (m0 + i)) * 512 + n] = v;
            }
        }
    }
}

// ---------------------------------------------------------------------------
// Kernel 4
// ---------------------------------------------------------------------------
__global__ __launch_bounds__(256) void gemm2_kernel(
    const float* __restrict__ h1, const float* __restrict__ W2,
    const float* __restrict__ b2,
    const float* __restrict__ n2_gamma, const float* __restrict__ n2_beta,
    const float* __restrict__ n2_mean, const float* __restrict__ n2_var,
    const float* __restrict__ bk_gamma, const float* __restrict__ bk_beta,
    const float* __restrict__ bk_mean, const float* __restrict__ bk_var,
    float* __restrict__ yv) {
    const int bn0 = blockIdx.x * 64, bm0 = blockIdx.y * 64;
    __shared__ float As[32][68];
    __shared__ float Bs[32][68];
    float acc[4][4] = {};
    const int t = threadIdx.x;
    const int tx = t & 15, ty = t >> 4;

    for (int k0 = 0; k0 < 512; k0 += 32) {
#pragma unroll
        for (int u = 0; u < 2; ++u) {
            const int idx = t + 256 * u;
            const int m = idx >> 3, kc = idx & 7;
            const float4 v = *(const float4*)(h1 + (size_t)(bm0 + m) * 512 + k0 + kc * 4);
            As[kc * 4 + 0][m] = v.x; As[kc * 4 + 1][m] = v.y;
            As[kc * 4 + 2][m] = v.z; As[kc * 4 + 3][m] = v.w;
            const float4 wv = *(const float4*)(W2 + (size_t)(bn0 + m) * 512 + k0 + kc * 4);
            Bs[kc * 4 + 0][m] = wv.x; Bs[kc * 4 + 1][m] = wv.y;
            Bs[kc * 4 + 2][m] = wv.z; Bs[kc * 4 + 3][m] = wv.w;
        }
        __syncthreads();
#pragma unroll 8
        for (int kk = 0; kk < 32; ++kk) {
            const float4 a = *(const float4*)&As[kk][ty * 4];
            const float4 wv = *(const float4*)&Bs[kk][tx * 4];
            const float av[4] = {a.x, a.y, a.z, a.w};
            const float bv[4] = {wv.x, wv.y, wv.z, wv.w};
#pragma unroll
            for (int i = 0; i < 4; ++i)
#pragma unroll
                for (int j = 0; j < 4; ++j) acc[i][j] += av[i] * bv[j];
        }
        __syncthreads();
    }

    const int m0 = bm0 + ty * 4, n0 = bn0 + tx * 4;
#pragma unroll
    for (int j = 0; j < 4; ++j) {
        const int n = n0 + j;
        const float b2v = b2[n];
        const float g1 = n2_gamma[n], be1 = n2_beta[n], mm1 = n2_mean[n], vv1 = n2_var[n];
#pragma unroll
        for (int i = 0; i < 4; ++i) {
            const int row = m0 + i;
            const int k = row >> 8, b = row & 255;
            float v = acc[i][j] + b2v;
            v = bn_apply(v, g1, be1, mm1, vv1);
            v = fmaxf(v, 0.f);
            const int pi = k * 128 + n;
            v = bn_apply(v, bk_gamma[pi], bk_beta[pi], bk_mean[pi], bk_var[pi]);
            yv[(size_t)b * 512 + pi] = v;
        }
    }
}

// ---------------------------------------------------------------------------
// Kernel 5: heads
// ---------------------------------------------------------------------------
__global__ __launch_bounds__(128) void head_kernel(
    const float* __restrict__ xg2, const float* __restrict__ yv,
    const float* __restrict__ Wcg, const float* __restrict__ bcg,
    const float* __restrict__ Wck, const float* __restrict__ bck,
    float* __restrict__ out) {
    const int b = blockIdx.x, t = threadIdx.x;
    __shared__ float xr[512], yr[512];
    ((float4*)xr)[t] = ((const float4*)(xg2 + (size_t)b * 512))[t];
    ((float4*)yr)[t] = ((const float4*)(yv + (size_t)b * 512))[t];
    __syncthreads();
    if (t < 51) {
        float acc = 0.f;
        const float4* wr = (const float4*)(Wcg + (size_t)t * 512);
        const float4* xv = (const float4*)xr;
#pragma unroll 8
        for (int p = 0; p < 128; ++p) {
            const float4 w4 = wr[p], v4 = xv[p];
            acc += w4.x * v4.x + w4.y * v4.y + w4.z * v4.z + w4.w * v4.w;
        }
        out[(size_t)b * 51 + t] = acc + bcg[t];
    } else if (t >= 64 && t < 115) {
        const int n = t - 64;
        float acc = 0.f;
        const float4* wr = (const float4*)(Wck + (size_t)n * 512);
        const float4* yv4 = (const float4*)yr;
#pragma unroll 8
        for (int p = 0; p < 128; ++p) {
            const float4 w4 = wr[p], v4 = yv4[p];
            acc += w4.x * v4.x + w4.y * v4.y + w4.z * v4.z + w4.w * v4.w;
        }
        out[(size_t)(B_ * 51) + (size_t)b * 51 + n] = acc + bck[n];
    }
}

// ---------------------------------------------------------------------------
extern "C" void kernel_launch(void* const* d_in, const int* in_sizes, int n_in,
                              void* d_out, int out_size, void* d_ws, size_t ws_size,
                              hipStream_t stream) {
    const float* x        = (const float*)d_in[0];
    const float* Wg       = (const float*)d_in[1];
    const float* bg       = (const float*)d_in[2];
    const float* g_gamma  = (const float*)d_in[3];
    const float* g_beta   = (const float*)d_in[4];
    const float* g_mean   = (const float*)d_in[5];
    const float* g_var    = (const float*)d_in[6];
    const float* gb_gamma = (const float*)d_in[7];
    const float* gb_beta  = (const float*)d_in[8];
    const float* gb_mean  = (const float*)d_in[9];
    const float* gb_var   = (const float*)d_in[10];
    const float* Wcg      = (const float*)d_in[11];
    const float* bcg      = (const float*)d_in[12];
    const float* W1       = (const float*)d_in[13];
    const float* b1       = (const float*)d_in[14];
    const float* n1_gamma = (const float*)d_in[15];
    const float* n1_beta  = (const float*)d_in[16];
    const float* n1_mean  = (const float*)d_in[17];
    const float* n1_var   = (const float*)d_in[18];
    const float* W2       = (const float*)d_in[19];
    const float* b2       = (const float*)d_in[20];
    const float* n2_gamma = (const float*)d_in[21];
    const float* n2_beta  = (const float*)d_in[22];
    const float* n2_mean  = (const float*)d_in[23];
    const float* n2_var   = (const float*)d_in[24];
    const float* bk_gamma = (const float*)d_in[25];
    const float* bk_beta  = (const float*)d_in[26];
    const float* bk_mean  = (const float*)d_in[27];
    const float* bk_var   = (const float*)d_in[28];
    const float* Wck      = (const float*)d_in[29];
    const float* bck      = (const float*)d_in[30];
    float* out = (float*)d_out;

    const size_t xt_elems    = (size_t)B_ * C_ * D_;           // 100,663,296 floats
    const size_t small_elems = 524288 + 131072 + 524288 + 131072; // pooled,xg2,h1,yv
    const size_t need_fast   = xt_elems * 4 + small_elems * 4 + 524288 + 256;

    if (ws_size >= need_fast) {
        float* xT          = (float*)d_ws;
        float* pooled      = xT + xt_elems;                      // 524288 f
        unsigned char* ids = (unsigned char*)(pooled + 524288);  // 524288 B
        float* xg2         = (float*)(ids + 524288);             // 131072 f
        float* h1          = xg2 + 131072;                       // 524288 f
        float* yv          = h1 + 524288;                        // 131072 f

        transpose_kernel<<<dim3(32, 3, B_), dim3(256), 0, stream>>>(x, xT);
        kmeans_fast_kernel<<<dim3(B_), dim3(1024), 0, stream>>>(x, xT, pooled, ids);
        gemm1_kernel<<<dim3(8, 4, 5), dim3(256), 0, stream>>>(
            pooled, ids, Wg, bg, g_gamma, g_beta, g_mean, g_var,
            gb_gamma, gb_beta, gb_mean, gb_var, W1, b1,
            n1_gamma, n1_beta, n1_mean, n1_var, xg2, h1);
        gemm2_kernel<<<dim3(2, 16), dim3(256), 0, stream>>>(
            h1, W2, b2, n2_gamma, n2_beta, n2_mean, n2_var,
            bk_gamma, bk_beta, bk_mean, bk_var, yv);
        head_kernel<<<dim3(B_), dim3(128), 0, stream>>>(xg2, yv, Wcg, bcg, Wck, bck, out);
    } else {
        float* pooled      = (float*)d_ws;                       // 524288 f
        unsigned char* ids = (unsigned char*)(pooled + 524288);  // 524288 B
        float* xg2         = (float*)(ids + 524288);             // 131072 f
        float* h1          = xg2 + 131072;                       // 524288 f
        float* yv          = h1 + 524288;                        // 131072 f

        pool_kernel<<<dim3((B_ * C_) / 4), dim3(256), 0, stream>>>(x, pooled);
        kmeans_fb_kernel<<<dim3(B_), dim3(512), 0, stream>>>(x, ids);
        gemm1_kernel<<<dim3(8, 4, 5), dim3(256), 0, stream>>>(
            pooled, ids, Wg, bg, g_gamma, g_beta, g_mean, g_var,
            gb_gamma, gb_beta, gb_mean, gb_var, W1, b1,
            n1_gamma, n1_beta, n1_mean, n1_var, xg2, h1);
        gemm2_kernel<<<dim3(2, 16), dim3(256), 0, stream>>>(
            h1, W2, b2, n2_gamma, n2_beta, n2_mean, n2_var,
            bk_gamma, bk_beta, bk_mean, bk_var, yv);
        head_kernel<<<dim3(B_), dim3(128), 0, stream>>>(xg2, yv, Wcg, bcg, Wck, bck, out);
    }
}

// Round 11
// 1790.807 us; speedup vs baseline: 2.2152x; 1.9645x over previous
//
#include <hip/hip_runtime.h>
#include <math.h>

#define B_   256
#define C_   2048
#define D_   192
#define EPSf 1e-5f
#define BLAS_Q 384   // OpenBLAS SGEMM_DEFAULT_Q — K-block size (validated in R5)

// ---------------------------------------------------------------------------
// numpy pairwise helpers (validated bit-exact in R5/R8/R10).
// ---------------------------------------------------------------------------
__device__ __forceinline__ float pw96_sq_f4(const float4* a4) {
    float r0 = 0.f, r1 = 0.f, r2 = 0.f, r3 = 0.f, r4 = 0.f, r5 = 0.f, r6 = 0.f, r7 = 0.f;
#pragma unroll
    for (int i = 0; i < 12; ++i) {
        const float4 v0 = a4[2 * i], v1 = a4[2 * i + 1];
        r0 += __fmul_rn(v0.x, v0.x); r1 += __fmul_rn(v0.y, v0.y);
        r2 += __fmul_rn(v0.z, v0.z); r3 += __fmul_rn(v0.w, v0.w);
        r4 += __fmul_rn(v1.x, v1.x); r5 += __fmul_rn(v1.y, v1.y);
        r6 += __fmul_rn(v1.z, v1.z); r7 += __fmul_rn(v1.w, v1.w);
    }
    return ((r0 + r1) + (r2 + r3)) + ((r4 + r5) + (r6 + r7));
}

__device__ __forceinline__ float pw96_sq_s(const float* a) {
    float r0 = 0.f, r1 = 0.f, r2 = 0.f, r3 = 0.f, r4 = 0.f, r5 = 0.f, r6 = 0.f, r7 = 0.f;
#pragma unroll
    for (int i = 0; i < 12; ++i) {
        r0 += __fmul_rn(a[8 * i + 0], a[8 * i + 0]);
        r1 += __fmul_rn(a[8 * i + 1], a[8 * i + 1]);
        r2 += __fmul_rn(a[8 * i + 2], a[8 * i + 2]);
        r3 += __fmul_rn(a[8 * i + 3], a[8 * i + 3]);
        r4 += __fmul_rn(a[8 * i + 4], a[8 * i + 4]);
        r5 += __fmul_rn(a[8 * i + 5], a[8 * i + 5]);
        r6 += __fmul_rn(a[8 * i + 6], a[8 * i + 6]);
        r7 += __fmul_rn(a[8 * i + 7], a[8 * i + 7]);
    }
    return ((r0 + r1) + (r2 + r3)) + ((r4 + r5) + (r6 + r7));
}

// ---------------------------------------------------------------------------
// Kernel 0 (fast path): tile-transpose x[b][c][d] -> xT[b][d][c].
// ---------------------------------------------------------------------------
__global__ __launch_bounds__(256) void transpose_kernel(const float* __restrict__ x,
                                                        float* __restrict__ xT) {
    const int b = blockIdx.z, c0 = blockIdx.x * 64, d0 = blockIdx.y * 64;
    const float* X = x + (size_t)b * (C_ * (size_t)D_);
    float* XT      = xT + (size_t)b * (C_ * (size_t)D_);
    __shared__ float tile[64][65];
    const int tx = threadIdx.x & 63, ty = threadIdx.x >> 6;
#pragma unroll
    for (int i = 0; i < 16; ++i) {
        const int c = ty + i * 4;
        tile[c][tx] = X[(size_t)(c0 + c) * D_ + d0 + tx];
    }
    __syncthreads();
#pragma unroll
    for (int i = 0; i < 16; ++i) {
        const int d = ty + i * 4;
        XT[(size_t)(d0 + d) * C_ + c0 + tx] = tile[tx][d];
    }
}

// ---------------------------------------------------------------------------
// Kernel 1 (fast path): fused pool + kmeans, 512 thr/block, 1 block/sample.
// KEY CHANGE vs R10: every streaming loop explicitly batches 8 independent
// float4 loads into registers BEFORE computing (guaranteed 8KB/wave in
// flight — the compiler's load->wait->use pattern in accumulator loops was
// limiting per-CU BW to ~6 GB/s). Thread t owns channels 4t..4t+3.
// All per-(channel,cluster) / per-(dim,cluster) FP chains bit-identical to
// the R5/R8/R10 PASS (d ascending / c ascending within Q=384 blocks).
// ---------------------------------------------------------------------------
__global__ __launch_bounds__(512) void kmeans_fast_kernel(const float* __restrict__ x,
                                                          const float* __restrict__ xT,
                                                          float* __restrict__ pooled,
                                                          unsigned char* __restrict__ ids_out) {
    const int b = blockIdx.x, t = threadIdx.x;
    const int lane = t & 63;
    const float* X   = x  + (size_t)b * (C_ * (size_t)D_);
    const float* XTb = xT + (size_t)b * (C_ * (size_t)D_);

    __shared__ __align__(16) float cent[4][192];
    __shared__ float xs_s[C_];
    __shared__ float part[6][4][192];
    __shared__ float cs4[4];
    __shared__ int   cnt[4];
    __shared__ int   changed;
    __shared__ unsigned char ids[C_];

    if (t < 192) {
        cent[0][t] = X[(size_t)0    * D_ + t];
        cent[1][t] = X[(size_t)512  * D_ + t];
        cent[2][t] = X[(size_t)1024 * D_ + t];
        cent[3][t] = X[(size_t)1536 * D_ + t];
    }

    // ---- init: xs (np pairwise 96+96, 8 accums) + pooled; batch-8 loads ----
    {
        const float4* pA = (const float4*)XTb + t;   // (d=0, channels 4t..4t+3)
        float sq0 = 0.f, sq1 = 0.f, sq2 = 0.f, sq3 = 0.f;
        float sm0 = 0.f, sm1 = 0.f, sm2 = 0.f, sm3 = 0.f;
#pragma unroll
        for (int blk = 0; blk < 2; ++blk) {
            float q[4][8], s[4][8];
#pragma unroll
            for (int ch = 0; ch < 4; ++ch)
#pragma unroll
                for (int j = 0; j < 8; ++j) { q[ch][j] = 0.f; s[ch][j] = 0.f; }
            for (int i = 0; i < 12; ++i) {
                float4 vb[8];
#pragma unroll
                for (int u = 0; u < 8; ++u) vb[u] = pA[(blk * 96 + 8 * i + u) << 9];
#pragma unroll
                for (int u = 0; u < 8; ++u) {
                    q[0][u] += __fmul_rn(vb[u].x, vb[u].x); s[0][u] += vb[u].x;
                    q[1][u] += __fmul_rn(vb[u].y, vb[u].y); s[1][u] += vb[u].y;
                    q[2][u] += __fmul_rn(vb[u].z, vb[u].z); s[2][u] += vb[u].z;
                    q[3][u] += __fmul_rn(vb[u].w, vb[u].w); s[3][u] += vb[u].w;
                }
            }
            sq0 += ((q[0][0] + q[0][1]) + (q[0][2] + q[0][3])) + ((q[0][4] + q[0][5]) + (q[0][6] + q[0][7]));
            sq1 += ((q[1][0] + q[1][1]) + (q[1][2] + q[1][3])) + ((q[1][4] + q[1][5]) + (q[1][6] + q[1][7]));
            sq2 += ((q[2][0] + q[2][1]) + (q[2][2] + q[2][3])) + ((q[2][4] + q[2][5]) + (q[2][6] + q[2][7]));
            sq3 += ((q[3][0] + q[3][1]) + (q[3][2] + q[3][3])) + ((q[3][4] + q[3][5]) + (q[3][6] + q[3][7]));
            sm0 += ((s[0][0] + s[0][1]) + (s[0][2] + s[0][3])) + ((s[0][4] + s[0][5]) + (s[0][6] + s[0][7]));
            sm1 += ((s[1][0] + s[1][1]) + (s[1][2] + s[1][3])) + ((s[1][4] + s[1][5]) + (s[1][6] + s[1][7]));
            sm2 += ((s[2][0] + s[2][1]) + (s[2][2] + s[2][3])) + ((s[2][4] + s[2][5]) + (s[2][6] + s[2][7]));
            sm3 += ((s[3][0] + s[3][1]) + (s[3][2] + s[3][3])) + ((s[3][4] + s[3][5]) + (s[3][6] + s[3][7]));
        }
        xs_s[4 * t + 0] = sq0; xs_s[4 * t + 1] = sq1;
        xs_s[4 * t + 2] = sq2; xs_s[4 * t + 3] = sq3;
        *(float4*)(pooled + (size_t)b * C_ + 4 * t) =
            make_float4(sm0 / 192.0f, sm1 / 192.0f, sm2 / 192.0f, sm3 / 192.0f);
        ids[4 * t + 0] = 255; ids[4 * t + 1] = 255;
        ids[4 * t + 2] = 255; ids[4 * t + 3] = 255;
    }
    __syncthreads();

    for (int iter = 0;; ++iter) {
        if (t < 4) {
            cs4[t] = pw96_sq_s(cent[t]) + pw96_sq_s(cent[t] + 96);
            cnt[t] = 0;
        }
        if (t == 0) changed = 0;
        __syncthreads();

        const float q0 = cs4[0], q1 = cs4[1], q2 = cs4[2], q3 = cs4[3];

        // ---- Phase A: 4 channels/thread; batch-8 float4 loads; chains
        // ascend d=0..191 per (channel, cluster) — R10 rounding order. ----
        int lc0 = 0, lc1 = 0, lc2 = 0, lc3 = 0, mych = 0;
        {
            const float4* pA = (const float4*)XTb + t;
            float acc[4][4] = {};   // [ch][k]
            for (int db = 0; db < 192; db += 8) {
                float4 vb[8];
#pragma unroll
                for (int u = 0; u < 8; ++u) vb[u] = pA[(db + u) << 9];
#pragma unroll
                for (int u = 0; u < 8; ++u) {
                    const int d = db + u;
                    const float c0 = cent[0][d], c1 = cent[1][d];
                    const float c2 = cent[2][d], c3 = cent[3][d];
                    acc[0][0] = fmaf(vb[u].x, c0, acc[0][0]);
                    acc[1][0] = fmaf(vb[u].y, c0, acc[1][0]);
                    acc[2][0] = fmaf(vb[u].z, c0, acc[2][0]);
                    acc[3][0] = fmaf(vb[u].w, c0, acc[3][0]);
                    acc[0][1] = fmaf(vb[u].x, c1, acc[0][1]);
                    acc[1][1] = fmaf(vb[u].y, c1, acc[1][1]);
                    acc[2][1] = fmaf(vb[u].z, c1, acc[2][1]);
                    acc[3][1] = fmaf(vb[u].w, c1, acc[3][1]);
                    acc[0][2] = fmaf(vb[u].x, c2, acc[0][2]);
                    acc[1][2] = fmaf(vb[u].y, c2, acc[1][2]);
                    acc[2][2] = fmaf(vb[u].z, c2, acc[2][2]);
                    acc[3][2] = fmaf(vb[u].w, c2, acc[3][2]);
                    acc[0][3] = fmaf(vb[u].x, c3, acc[0][3]);
                    acc[1][3] = fmaf(vb[u].y, c3, acc[1][3]);
                    acc[2][3] = fmaf(vb[u].z, c3, acc[2][3]);
                    acc[3][3] = fmaf(vb[u].w, c3, acc[3][3]);
                }
            }
#pragma unroll
            for (int ch = 0; ch < 4; ++ch) {
                const int c = 4 * t + ch;
                const float xv = xs_s[c];
                const float e0 = (xv - 2.0f * acc[ch][0]) + q0;
                const float e1 = (xv - 2.0f * acc[ch][1]) + q1;
                const float e2 = (xv - 2.0f * acc[ch][2]) + q2;
                const float e3 = (xv - 2.0f * acc[ch][3]) + q3;
                int id = 0; float best = e0;
                if (e1 < best) { best = e1; id = 1; }
                if (e2 < best) { best = e2; id = 2; }
                if (e3 < best) { best = e3; id = 3; }
                lc0 += (id == 0); lc1 += (id == 1); lc2 += (id == 2); lc3 += (id == 3);
                mych |= (ids[c] != (unsigned char)id);
                ids[c] = (unsigned char)id;
            }
        }
#pragma unroll
        for (int off = 32; off > 0; off >>= 1) {
            lc0 += __shfl_down(lc0, off);
            lc1 += __shfl_down(lc1, off);
            lc2 += __shfl_down(lc2, off);
            lc3 += __shfl_down(lc3, off);
        }
        if (lane == 0) {
            atomicAdd(&cnt[0], lc0); atomicAdd(&cnt[1], lc1);
            atomicAdd(&cnt[2], lc2); atomicAdd(&cnt[3], lc3);
        }
        if (mych) changed = 1;
        __syncthreads();

        if (changed == 0 || iter == 10) break;   // converged -> exact fixed point

        // ---- Phase B: 288 tasks (kb, dgroup of 4 dims); batch-8 over c;
        // per-(dim,k) chains ascend c within clamped Q=384 blocks. ----
        if (t < 288) {
            const int kb = t / 48;
            const int dg = t - kb * 48;
            const int cb = kb * BLAS_Q;
            const int ce = (cb + BLAS_Q < C_) ? (cb + BLAS_Q) : C_;
            const float4* pB = (const float4*)X + (size_t)cb * 48 + dg;
            float s[4][4] = {};   // [dim j][k]
            for (int c0i = 0; c0i < ce - cb; c0i += 8) {
                float4 vb[8];
#pragma unroll
                for (int u = 0; u < 8; ++u) vb[u] = pB[(size_t)(c0i + u) * 48];
#pragma unroll
                for (int u = 0; u < 8; ++u) {
                    const int id = ids[cb + c0i + u];
                    s[0][0] += (id == 0) ? vb[u].x : 0.0f;
                    s[1][0] += (id == 0) ? vb[u].y : 0.0f;
                    s[2][0] += (id == 0) ? vb[u].z : 0.0f;
                    s[3][0] += (id == 0) ? vb[u].w : 0.0f;
                    s[0][1] += (id == 1) ? vb[u].x : 0.0f;
                    s[1][1] += (id == 1) ? vb[u].y : 0.0f;
                    s[2][1] += (id == 1) ? vb[u].z : 0.0f;
                    s[3][1] += (id == 1) ? vb[u].w : 0.0f;
                    s[0][2] += (id == 2) ? vb[u].x : 0.0f;
                    s[1][2] += (id == 2) ? vb[u].y : 0.0f;
                    s[2][2] += (id == 2) ? vb[u].z : 0.0f;
                    s[3][2] += (id == 2) ? vb[u].w : 0.0f;
                    s[0][3] += (id == 3) ? vb[u].x : 0.0f;
                    s[1][3] += (id == 3) ? vb[u].y : 0.0f;
                    s[2][3] += (id == 3) ? vb[u].z : 0.0f;
                    s[3][3] += (id == 3) ? vb[u].w : 0.0f;
                }
            }
#pragma unroll
            for (int k = 0; k < 4; ++k) {
                part[kb][k][4 * dg + 0] = s[0][k];
                part[kb][k][4 * dg + 1] = s[1][k];
                part[kb][k][4 * dg + 2] = s[2][k];
                part[kb][k][4 * dg + 3] = s[3][k];
            }
        }
        __syncthreads();
        if (t < 192) {
#pragma unroll
            for (int k = 0; k < 4; ++k) {
                float tt = part[0][k][t];          // = 0 + p0 exactly (R5 order)
                tt += part[1][k][t];
                tt += part[2][k][t];
                tt += part[3][k][t];
                tt += part[4][k][t];
                tt += part[5][k][t];
                if (cnt[k] > 0) cent[k][t] = tt / (float)cnt[k];
            }
        }
        __syncthreads();
    }

    *(uchar4*)(ids_out + (size_t)b * C_ + 4 * t) = *(uchar4*)&ids[4 * t];
}

// ---------------------------------------------------------------------------
// FALLBACK (ws too small): exact R8 PASS kernels.
// ---------------------------------------------------------------------------
__global__ __launch_bounds__(256) void pool_kernel(const float* __restrict__ x,
                                                   float* __restrict__ pooled) {
    const int row  = blockIdx.x * 4 + (threadIdx.x >> 6);
    const int lane = threadIdx.x & 63;
    const float* r = x + (size_t)row * D_;
    float s = 0.f;
    if (lane < 48) {
        const float4 v = ((const float4*)r)[lane];
        s = v.x + v.y + v.z + v.w;
    }
#pragma unroll
    for (int off = 32; off > 0; off >>= 1) s += __shfl_down(s, off);
    if (lane == 0) pooled[row] = s * (1.f / 192.f);
}

__global__ __launch_bounds__(512) void kmeans_fb_kernel(const float* __restrict__ x,
                                                        unsigned char* __restrict__ ids_out) {
    const int b = blockIdx.x, t = threadIdx.x;
    const int lane = t & 63;
    const float* X = x + (size_t)b * (C_ * (size_t)D_);

    __shared__ __align__(16) float cent[4][192];
    __shared__ float xs_s[C_];
    __shared__ float cs4[4];
    __shared__ int   cnt[4];
    __shared__ int   changed;
    __shared__ unsigned char ids[C_];

    if (t < 192) {
        cent[0][t] = X[(size_t)0    * D_ + t];
        cent[1][t] = X[(size_t)512  * D_ + t];
        cent[2][t] = X[(size_t)1024 * D_ + t];
        cent[3][t] = X[(size_t)1536 * D_ + t];
    }
    for (int c = t; c < C_; c += 512) {
        const float4* r4 = (const float4*)(X + (size_t)c * D_);
        xs_s[c] = pw96_sq_f4(r4) + pw96_sq_f4(r4 + 24);
        ids[c]  = 255;
    }
    __syncthreads();

    for (int iter = 0;; ++iter) {
        if (t < 4) {
            cs4[t] = pw96_sq_s(cent[t]) + pw96_sq_s(cent[t] + 96);
            cnt[t] = 0;
        }
        if (t == 0) changed = 0;
        __syncthreads();

        const float q0 = cs4[0], q1 = cs4[1], q2 = cs4[2], q3 = cs4[3];
        int lc0 = 0, lc1 = 0, lc2 = 0, lc3 = 0, mych = 0;
        for (int j = 0; j < 4; ++j) {
            const int c = t + 512 * j;
            const float4* r4 = (const float4*)(X + (size_t)c * D_);
            float d0 = 0.f, d1 = 0.f, d2 = 0.f, d3 = 0.f;
#pragma unroll 8
            for (int i = 0; i < 48; ++i) {
                const float4 a  = r4[i];
                const float4 c0 = *(const float4*)&cent[0][4 * i];
                const float4 c1 = *(const float4*)&cent[1][4 * i];
                const float4 c2 = *(const float4*)&cent[2][4 * i];
                const float4 c3 = *(const float4*)&cent[3][4 * i];
                d0 = fmaf(a.x, c0.x, d0); d0 = fmaf(a.y, c0.y, d0);
                d0 = fmaf(a.z, c0.z, d0); d0 = fmaf(a.w, c0.w, d0);
                d1 = fmaf(a.x, c1.x, d1); d1 = fmaf(a.y, c1.y, d1);
                d1 = fmaf(a.z, c1.z, d1); d1 = fmaf(a.w, c1.w, d1);
                d2 = fmaf(a.x, c2.x, d2); d2 = fmaf(a.y, c2.y, d2);
                d2 = fmaf(a.z, c2.z, d2); d2 = fmaf(a.w, c2.w, d2);
                d3 = fmaf(a.x, c3.x, d3); d3 = fmaf(a.y, c3.y, d3);
                d3 = fmaf(a.z, c3.z, d3); d3 = fmaf(a.w, c3.w, d3);
            }
            const float xv = xs_s[c];
            const float e0 = (xv - 2.0f * d0) + q0;
            const float e1 = (xv - 2.0f * d1) + q1;
            const float e2 = (xv - 2.0f * d2) + q2;
            const float e3 = (xv - 2.0f * d3) + q3;
            int id = 0; float best = e0;
            if (e1 < best) { best = e1; id = 1; }
            if (e2 < best) { best = e2; id = 2; }
            if (e3 < best) { best = e3; id = 3; }
            lc0 += (id == 0); lc1 += (id == 1); lc2 += (id == 2); lc3 += (id == 3);
            mych |= (ids[c] != (unsigned char)id);
            ids[c] = (unsigned char)id;
        }
#pragma unroll
        for (int off = 32; off > 0; off >>= 1) {
            lc0 += __shfl_down(lc0, off);
            lc1 += __shfl_down(lc1, off);
            lc2 += __shfl_down(lc2, off);
            lc3 += __shfl_down(lc3, off);
        }
        if (lane == 0) {
            atomicAdd(&cnt[0], lc0); atomicAdd(&cnt[1], lc1);
            atomicAdd(&cnt[2], lc2); atomicAdd(&cnt[3], lc3);
        }
        if (mych) changed = 1;
        __syncthreads();

        if (changed == 0 || iter == 10) break;

        if (t < 192) {
            float t0 = 0.f, t1 = 0.f, t2 = 0.f, t3 = 0.f;
            for (int kb = 0; kb < C_; kb += BLAS_Q) {
                const int ke = (kb + BLAS_Q < C_) ? (kb + BLAS_Q) : C_;
                float s0 = 0.f, s1 = 0.f, s2 = 0.f, s3 = 0.f;
                for (int c = kb; c < ke; ++c) {
                    const float xv = X[(size_t)c * D_ + t];
                    const int id = ids[c];
                    s0 += (id == 0) ? xv : 0.0f;
                    s1 += (id == 1) ? xv : 0.0f;
                    s2 += (id == 2) ? xv : 0.0f;
                    s3 += (id == 3) ? xv : 0.0f;
                }
                t0 += s0; t1 += s1; t2 += s2; t3 += s3;
            }
            if (cnt[0] > 0) cent[0][t] = t0 / (float)cnt[0];
            if (cnt[1] > 0) cent[1][t] = t1 / (float)cnt[1];
            if (cnt[2] > 0) cent[2][t] = t2 / (float)cnt[2];
            if (cnt[3] > 0) cent[3][t] = t3 / (float)cnt[3];
        }
        __syncthreads();
    }

    for (int c = t; c < C_; c += 512) ids_out[(size_t)b * C_ + c] = ids[c];
}

// ---------------------------------------------------------------------------
__device__ __forceinline__ float bn_apply(float v, float g, float be, float m, float va) {
    return (v - m) / sqrtf(va + EPSf) * g + be;
}

// ---------------------------------------------------------------------------
// Kernel 3: batched 64x64-tiled GEMM, M=256, N=512, K=2048.
// ---------------------------------------------------------------------------
__global__ __launch_bounds__(256) void gemm1_kernel(
    const float* __restrict__ pooled, const unsigned char* __restrict__ ids,
    const float* __restrict__ Wg, const float* __restrict__ bg,
    const float* __restrict__ g_gamma, const float* __restrict__ g_beta,
    const float* __restrict__ g_mean, const float* __restrict__ g_var,
    const float* __restrict__ gb_gamma, const float* __restrict__ gb_beta,
    const float* __restrict__ gb_mean, const float* __restrict__ gb_var,
    const float* __restrict__ W1, const float* __restrict__ b1,
    const float* __restrict__ n1_gamma, const float* __restrict__ n1_beta,
    const float* __restrict__ n1_mean, const float* __restrict__ n1_var,
    float* __restrict__ xg2, float* __restrict__ h1) {
    const int z = blockIdx.z;
    const int bn0 = blockIdx.x * 64, bm0 = blockIdx.y * 64;
    const float* Bmat = (z == 0) ? Wg : W1;
    __shared__ float As[32][68];
    __shared__ float Bs[32][68];
    float acc[4][4] = {};
    const int t = threadIdx.x;
    const int tx = t & 15, ty = t >> 4;

    for (int k0 = 0; k0 < 2048; k0 += 32) {
#pragma unroll
        for (int u = 0; u < 2; ++u) {
            const int idx = t + 256 * u;
            const int m = idx >> 3, kc = idx & 7;
            float4 v = *(const float4*)(pooled + (size_t)(bm0 + m) * 2048 + k0 + kc * 4);
            if (z > 0) {
                const unsigned int uu =
                    *(const unsigned int*)(ids + (size_t)(bm0 + m) * 2048 + k0 + kc * 4);
                const unsigned int k = (unsigned int)(z - 1);
                v.x = ((uu & 0xffu) == k) ? v.x : 0.f;
                v.y = (((uu >> 8) & 0xffu) == k) ? v.y : 0.f;
                v.z = (((uu >> 16) & 0xffu) == k) ? v.z : 0.f;
                v.w = (((uu >> 24) & 0xffu) == k) ? v.w : 0.f;
            }
            As[kc * 4 + 0][m] = v.x; As[kc * 4 + 1][m] = v.y;
            As[kc * 4 + 2][m] = v.z; As[kc * 4 + 3][m] = v.w;
            const float4 wv = *(const float4*)(Bmat + (size_t)(bn0 + m) * 2048 + k0 + kc * 4);
            Bs[kc * 4 + 0][m] = wv.x; Bs[kc * 4 + 1][m] = wv.y;
            Bs[kc * 4 + 2][m] = wv.z; Bs[kc * 4 + 3][m] = wv.w;
        }
        __syncthreads();
#pragma unroll 8
        for (int kk = 0; kk < 32; ++kk) {
            const float4 a = *(const float4*)&As[kk][ty * 4];
            const float4 wv = *(const float4*)&Bs[kk][tx * 4];
            const float av[4] = {a.x, a.y, a.z, a.w};
            const float bv[4] = {wv.x, wv.y, wv.z, wv.w};
#pragma unroll
            for (int i = 0; i < 4; ++i)
#pragma unroll
                for (int j = 0; j < 4; ++j) acc[i][j] += av[i] * bv[j];
        }
        __syncthreads();
    }

    const int m0 = bm0 + ty * 4, n0 = bn0 + tx * 4;
    if (z == 0) {
#pragma unroll
        for (int j = 0; j < 4; ++j) {
            const int n = n0 + j;
            const float bgv = bg[n];
            const float g1 = g_gamma[n], be1 = g_beta[n], mm1 = g_mean[n], vv1 = g_var[n];
            const float g2 = gb_gamma[n], be2 = gb_beta[n], mm2 = gb_mean[n], vv2 = gb_var[n];
#pragma unroll
            for (int i = 0; i < 4; ++i) {
                float v = acc[i][j] + bgv;
                v = bn_apply(v, g1, be1, mm1, vv1);
                v = fmaxf(v, 0.f);
                v = bn_apply(v, g2, be2, mm2, vv2);
                xg2[(size_t)(m0 + i) * 512 + n] = v;
            }
        }
    } else {
        const int k = z - 1;
#pragma unroll
        for (int j = 0; j < 4; ++j) {
            const int n = n0 + j;
            const float b1v = b1[n];
            const float g1 = n1_gamma[n], be1 = n1_beta[n], mm1 = n1_mean[n], vv1 = n1_var[n];
#pragma unroll
            for (int i = 0; i < 4; ++i) {
                float v = acc[i][j] + b1v;
                v = bn_apply(v, g1, be1, mm1, vv1);
                v = fmaxf(v, 0.f);
                h1[((size_t)k * 256 + (m0 + i)) * 512 + n] = v;
            }
        }
    }
}

// ---------------------------------------------------------------------------
// Kernel 4
// ---------------------------------------------------------------------------
__global__ __launch_bounds__(256) void gemm2_kernel(
    const float* __restrict__ h1, const float* __restrict__ W2,
    const float* __restrict__ b2,
    const float* __restrict__ n2_gamma, const float* __restrict__ n2_beta,
    const float* __restrict__ n2_mean, const float* __restrict__ n2_var,
    const float* __restrict__ bk_gamma, const float* __restrict__ bk_beta,
    const float* __restrict__ bk_mean, const float* __restrict__ bk_var,
    float* __restrict__ yv) {
    const int bn0 = blockIdx.x * 64, bm0 = blockIdx.y * 64;
    __shared__ float As[32][68];
    __shared__ float Bs[32][68];
    float acc[4][4] = {};
    const int t = threadIdx.x;
    const int tx = t & 15, ty = t >> 4;

    for (int k0 = 0; k0 < 512; k0 += 32) {
#pragma unroll
        for (int u = 0; u < 2; ++u) {
            const int idx = t + 256 * u;
            const int m = idx >> 3, kc = idx & 7;
            const float4 v = *(const float4*)(h1 + (size_t)(bm0 + m) * 512 + k0 + kc * 4);
            As[kc * 4 + 0][m] = v.x; As[kc * 4 + 1][m] = v.y;
            As[kc * 4 + 2][m] = v.z; As[kc * 4 + 3][m] = v.w;
            const float4 wv = *(const float4*)(W2 + (size_t)(bn0 + m) * 512 + k0 + kc * 4);
            Bs[kc * 4 + 0][m] = wv.x; Bs[kc * 4 + 1][m] = wv.y;
            Bs[kc * 4 + 2][m] = wv.z; Bs[kc * 4 + 3][m] = wv.w;
        }
        __syncthreads();
#pragma unroll 8
        for (int kk = 0; kk < 32; ++kk) {
            const float4 a = *(const float4*)&As[kk][ty * 4];
            const float4 wv = *(const float4*)&Bs[kk][tx * 4];
            const float av[4] = {a.x, a.y, a.z, a.w};
            const float bv[4] = {wv.x, wv.y, wv.z, wv.w};
#pragma unroll
            for (int i = 0; i < 4; ++i)
#pragma unroll
                for (int j = 0; j < 4; ++j) acc[i][j] += av[i] * bv[j];
        }
        __syncthreads();
    }

    const int m0 = bm0 + ty * 4, n0 = bn0 + tx * 4;
#pragma unroll
    for (int j = 0; j < 4; ++j) {
        const int n = n0 + j;
        const float b2v = b2[n];
        const float g1 = n2_gamma[n], be1 = n2_beta[n], mm1 = n2_mean[n], vv1 = n2_var[n];
#pragma unroll
        for (int i = 0; i < 4; ++i) {
            const int row = m0 + i;
            const int k = row >> 8, b = row & 255;
            float v = acc[i][j] + b2v;
            v = bn_apply(v, g1, be1, mm1, vv1);
            v = fmaxf(v, 0.f);
            const int pi = k * 128 + n;
            v = bn_apply(v, bk_gamma[pi], bk_beta[pi], bk_mean[pi], bk_var[pi]);
            yv[(size_t)b * 512 + pi] = v;
        }
    }
}

// ---------------------------------------------------------------------------
// Kernel 5: heads
// ---------------------------------------------------------------------------
__global__ __launch_bounds__(128) void head_kernel(
    const float* __restrict__ xg2, const float* __restrict__ yv,
    const float* __restrict__ Wcg, const float* __restrict__ bcg,
    const float* __restrict__ Wck, const float* __restrict__ bck,
    float* __restrict__ out) {
    const int b = blockIdx.x, t = threadIdx.x;
    __shared__ float xr[512], yr[512];
    ((float4*)xr)[t] = ((const float4*)(xg2 + (size_t)b * 512))[t];
    ((float4*)yr)[t] = ((const float4*)(yv + (size_t)b * 512))[t];
    __syncthreads();
    if (t < 51) {
        float acc = 0.f;
        const float4* wr = (const float4*)(Wcg + (size_t)t * 512);
        const float4* xv = (const float4*)xr;
#pragma unroll 8
        for (int p = 0; p < 128; ++p) {
            const float4 w4 = wr[p], v4 = xv[p];
            acc += w4.x * v4.x + w4.y * v4.y + w4.z * v4.z + w4.w * v4.w;
        }
        out[(size_t)b * 51 + t] = acc + bcg[t];
    } else if (t >= 64 && t < 115) {
        const int n = t - 64;
        float acc = 0.f;
        const float4* wr = (const float4*)(Wck + (size_t)n * 512);
        const float4* yv4 = (const float4*)yr;
#pragma unroll 8
        for (int p = 0; p < 128; ++p) {
            const float4 w4 = wr[p], v4 = yv4[p];
            acc += w4.x * v4.x + w4.y * v4.y + w4.z * v4.z + w4.w * v4.w;
        }
        out[(size_t)(B_ * 51) + (size_t)b * 51 + n] = acc + bck[n];
    }
}

// ---------------------------------------------------------------------------
extern "C" void kernel_launch(void* const* d_in, const int* in_sizes, int n_in,
                              void* d_out, int out_size, void* d_ws, size_t ws_size,
                              hipStream_t stream) {
    const float* x        = (const float*)d_in[0];
    const float* Wg       = (const float*)d_in[1];
    const float* bg       = (const float*)d_in[2];
    const float* g_gamma  = (const float*)d_in[3];
    const float* g_beta   = (const float*)d_in[4];
    const float* g_mean   = (const float*)d_in[5];
    const float* g_var    = (const float*)d_in[6];
    const float* gb_gamma = (const float*)d_in[7];
    const float* gb_beta  = (const float*)d_in[8];
    const float* gb_mean  = (const float*)d_in[9];
    const float* gb_var   = (const float*)d_in[10];
    const float* Wcg      = (const float*)d_in[11];
    const float* bcg      = (const float*)d_in[12];
    const float* W1       = (const float*)d_in[13];
    const float* b1       = (const float*)d_in[14];
    const float* n1_gamma = (const float*)d_in[15];
    const float* n1_beta  = (const float*)d_in[16];
    const float* n1_mean  = (const float*)d_in[17];
    const float* n1_var   = (const float*)d_in[18];
    const float* W2       = (const float*)d_in[19];
    const float* b2       = (const float*)d_in[20];
    const float* n2_gamma = (const float*)d_in[21];
    const float* n2_beta  = (const float*)d_in[22];
    const float* n2_mean  = (const float*)d_in[23];
    const float* n2_var   = (const float*)d_in[24];
    const float* bk_gamma = (const float*)d_in[25];
    const float* bk_beta  = (const float*)d_in[26];
    const float* bk_mean  = (const float*)d_in[27];
    const float* bk_var   = (const float*)d_in[28];
    const float* Wck      = (const float*)d_in[29];
    const float* bck      = (const float*)d_in[30];
    float* out = (float*)d_out;

    const size_t xt_elems    = (size_t)B_ * C_ * D_;              // 100,663,296 floats
    const size_t small_elems = 524288 + 131072 + 524288 + 131072; // pooled,xg2,h1,yv
    const size_t need_fast   = xt_elems * 4 + small_elems * 4 + 524288 + 256;

    if (ws_size >= need_fast) {
        float* xT          = (float*)d_ws;
        float* pooled      = xT + xt_elems;                      // 524288 f
        unsigned char* ids = (unsigned char*)(pooled + 524288);  // 524288 B
        float* xg2         = (float*)(ids + 524288);             // 131072 f
        float* h1          = xg2 + 131072;                       // 524288 f
        float* yv          = h1 + 524288;                        // 131072 f

        transpose_kernel<<<dim3(32, 3, B_), dim3(256), 0, stream>>>(x, xT);
        kmeans_fast_kernel<<<dim3(B_), dim3(512), 0, stream>>>(x, xT, pooled, ids);
        gemm1_kernel<<<dim3(8, 4, 5), dim3(256), 0, stream>>>(
            pooled, ids, Wg, bg, g_gamma, g_beta, g_mean, g_var,
            gb_gamma, gb_beta, gb_mean, gb_var, W1, b1,
            n1_gamma, n1_beta, n1_mean, n1_var, xg2, h1);
        gemm2_kernel<<<dim3(2, 16), dim3(256), 0, stream>>>(
            h1, W2, b2, n2_gamma, n2_beta, n2_mean, n2_var,
            bk_gamma, bk_beta, bk_mean, bk_var, yv);
        head_kernel<<<dim3(B_), dim3(128), 0, stream>>>(xg2, yv, Wcg, bcg, Wck, bck, out);
    } else {
        float* pooled      = (float*)d_ws;                       // 524288 f
        unsigned char* ids = (unsigned char*)(pooled + 524288);  // 524288 B
        float* xg2         = (float*)(ids + 524288);             // 131072 f
        float* h1          = xg2 + 131072;                       // 524288 f
        float* yv          = h1 + 524288;                        // 131072 f

        pool_kernel<<<dim3((B_ * C_) / 4), dim3(256), 0, stream>>>(x, pooled);
        kmeans_fb_kernel<<<dim3(B_), dim3(512), 0, stream>>>(x, ids);
        gemm1_kernel<<<dim3(8, 4, 5), dim3(256), 0, stream>>>(
            pooled, ids, Wg, bg, g_gamma, g_beta, g_mean, g_var,
            gb_gamma, gb_beta, gb_mean, gb_var, W1, b1,
            n1_gamma, n1_beta, n1_mean, n1_var, xg2, h1);
        gemm2_kernel<<<dim3(2, 16), dim3(256), 0, stream>>>(
            h1, W2, b2, n2_gamma, n2_beta, n2_mean, n2_var,
            bk_gamma, bk_beta, bk_mean, bk_var, yv);
        head_kernel<<<dim3(B_), dim3(128), 0, stream>>>(xg2, yv, Wcg, bcg, Wck, bck, out);
    }
}